// Round 1
// baseline (278.249 us; speedup 1.0000x reference)
//
#include <hip/hip_runtime.h>
#include <math.h>

// GCN graph-matching net, restructured:
//  - K's off-diag values are only used via (K != 0)  ->  pattern = m[a]*m[b]*[i1!=i2]*[j1!=j2]
//    with m[i,j] = (cls1[i]==cls2[j]); edge MLPs / edge cosines are dead code.
//  - normA @ u collapses to O(N):  o[a] = dinv[a]*((1+m)*dinv*u + m*(W - WR_i - WC_j + z[a])),
//    z = m .* dinv .* u,  W/WR/WC = total/row/col sums of z.
//  - x stays rank<=7: components {x0, v0, s0, w0, u0, e0, s1} with 16-dim directions; the
//    sinkhorn inputs and final scores are scalar combos of these N-vectors.
// Single workgroup of 1024 threads; N-vectors in d_ws, sinkhorn matrix + reductions in LDS.

#define TAU_F 0.05f

__device__ __forceinline__ float wave_max64(float v) {
    #pragma unroll
    for (int off = 32; off > 0; off >>= 1) v = fmaxf(v, __shfl_xor(v, off, 64));
    return v;
}
__device__ __forceinline__ float wave_sum64(float v) {
    #pragma unroll
    for (int off = 32; off > 0; off >>= 1) v += __shfl_xor(v, off, 64);
    return v;
}

// 20 alternating row/col logsumexp normalizations on 64x64 (stride-65 padded) LDS matrix.
// Leaves log-values; caller applies expf. All 1024 threads must call.
__device__ void sinkhorn_inplace(float* sk, int tid) {
    const int wave = tid >> 6, lane = tid & 63;
    for (int it = 0; it < 20; ++it) {
        __syncthreads();
        if ((it & 1) == 0) {                 // axis=1: normalize rows
            #pragma unroll
            for (int p = 0; p < 4; ++p) {
                int r = wave + (p << 4);
                float v = sk[r * 65 + lane];
                float mx = wave_max64(v);
                float sm = wave_sum64(expf(v - mx));
                sk[r * 65 + lane] = v - (logf(sm) + mx);
            }
        } else {                             // axis=0: normalize cols
            #pragma unroll
            for (int p = 0; p < 4; ++p) {
                int c = wave + (p << 4);
                float v = sk[lane * 65 + c];
                float mx = wave_max64(v);
                float sm = wave_sum64(expf(v - mx));
                sk[lane * 65 + c] = v - (logf(sm) + mx);
            }
        }
    }
    __syncthreads();
}

// o = normA @ u  (u==nullptr means u = ones). If outv!=nullptr write o there,
// else tacc[a] += ct*o, sacc[a] += cs*o. All 1024 threads must call.
__device__ void norma_matvec(const float* u, float* outv,
                             float* tacc, float* sacc, float ct, float cs,
                             const float* dinv, const float* cls1, const float* cls2,
                             float* WR, float* WC, float* pcol, float* Wtot, int tid) {
    const int wave = tid >> 6, lane = tid & 63;
    // row sums of z = m .* dinv .* u  (wave per row, 4 rows/wave)
    #pragma unroll
    for (int p = 0; p < 4; ++p) {
        int r = wave + (p << 4);
        int a = r * 64 + lane;
        float mm = (cls1[r] == cls2[lane]) ? 1.0f : 0.0f;
        float z = mm * dinv[a] * (u ? u[a] : 1.0f);
        float s = wave_sum64(z);
        if (lane == 0) WR[r] = s;
    }
    // column partials (coalesced reads, padded LDS partials)
    {
        int j = tid & 63, w = tid >> 6;
        float acc = 0.0f;
        #pragma unroll
        for (int k = 0; k < 4; ++k) {
            int a = tid + (k << 10);
            int i = a >> 6;
            float mm = (cls1[i] == cls2[j]) ? 1.0f : 0.0f;
            acc += mm * dinv[a] * (u ? u[a] : 1.0f);
        }
        pcol[w * 65 + j] = acc;
    }
    __syncthreads();
    if (tid < 64) {
        float s = 0.0f;
        #pragma unroll
        for (int w = 0; w < 16; ++w) s += pcol[w * 65 + tid];
        WC[tid] = s;
    } else if (tid == 64) {
        float s = 0.0f;
        for (int r = 0; r < 64; ++r) s += WR[r];
        Wtot[0] = s;
    }
    __syncthreads();
    const float Wt = Wtot[0];
    #pragma unroll
    for (int p = 0; p < 4; ++p) {
        int a = tid + (p << 10);
        int i = a >> 6, j = a & 63;
        float mm = (cls1[i] == cls2[j]) ? 1.0f : 0.0f;
        float d = dinv[a];
        float uv = u ? u[a] : 1.0f;
        float za = mm * d * uv;
        float o = d * ((1.0f + mm) * d * uv + mm * (Wt - WR[i] - WC[j] + za));
        if (outv) outv[a] = o;
        else { tacc[a] += ct * o; sacc[a] += cs * o; }
    }
    __syncthreads();  // protect WR/WC/pcol for next call
}

extern "C" __global__ __launch_bounds__(1024)
void gcn_match_kernel(const float* ego, const float* cav,
                      const float* nw1, const float* nb1, const float* nw2, const float* nb2,
                      const float* sw0, const float* sb0, const float* cw0, const float* cb0,
                      const float* kw0, const float* kb0,
                      const float* sw1, const float* sb1, const float* cw1, const float* cb1,
                      const float* kw1, const float* kb1,
                      const float* fcw, const float* fcb,
                      float* ws, float* out) {
    __shared__ float sh_h[64 * 65];      // MLP hidden; later aliased as dinv (4096 floats)
    __shared__ float sh_f1[64 * 33];
    __shared__ float sh_f2[64 * 33];
    __shared__ float sh_sk[64 * 65];     // sinkhorn matrix
    __shared__ float sh_pcol[16 * 65];
    __shared__ float sh_WR[64], sh_WC[64];
    __shared__ float sh_R[64], sh_C[64];
    __shared__ float sh_cls1[64], sh_cls2[64], sh_cf1[64], sh_cf2[64];
    __shared__ float sh_n1[64], sh_n2[64];
    __shared__ float sh_avec[7 * 16];
    __shared__ float sh_coef[18];
    __shared__ float sh_W[1], sh_T[1];

    const int tid = threadIdx.x;
    float* dinv = sh_h;  // alias: sh_h free after f1/f2 are built

    float* x0   = ws;
    float* v0   = ws + 4096;
    float* s0   = ws + 8192;
    float* tacc = ws + 12288;
    float* sacc = ws + 16384;

    // ---- A: per-node cls / confidence ----
    if (tid < 64) { sh_cls1[tid] = ego[tid * 8 + 6]; sh_cf1[tid] = ego[tid * 8 + 7]; }
    else if (tid < 128) { int j = tid - 64; sh_cls2[j] = cav[j * 8 + 6]; sh_cf2[j] = cav[j * 8 + 7]; }
    __syncthreads();

    // ---- B: node MLP: f = relu(x5 @ W1 + b1) @ W2 + b2 ----
    #pragma unroll
    for (int p = 0; p < 4; ++p) {  // ego hidden
        int item = tid + (p << 10);
        int i = item >> 6, k = item & 63;
        float acc = nb1[k];
        #pragma unroll
        for (int f = 0; f < 5; ++f) acc += ego[i * 8 + 1 + f] * nw1[f * 64 + k];
        sh_h[i * 65 + k] = fmaxf(acc, 0.0f);
    }
    __syncthreads();
    #pragma unroll
    for (int p = 0; p < 2; ++p) {  // f1
        int item = tid + (p << 10);
        int i = item >> 5, o = item & 31;
        float acc = nb2[o];
        for (int k = 0; k < 64; ++k) acc += sh_h[i * 65 + k] * nw2[k * 32 + o];
        sh_f1[i * 33 + o] = acc;
    }
    __syncthreads();
    #pragma unroll
    for (int p = 0; p < 4; ++p) {  // cav hidden
        int item = tid + (p << 10);
        int i = item >> 6, k = item & 63;
        float acc = nb1[k];
        #pragma unroll
        for (int f = 0; f < 5; ++f) acc += cav[i * 8 + 1 + f] * nw1[f * 64 + k];
        sh_h[i * 65 + k] = fmaxf(acc, 0.0f);
    }
    __syncthreads();
    #pragma unroll
    for (int p = 0; p < 2; ++p) {  // f2
        int item = tid + (p << 10);
        int i = item >> 5, o = item & 31;
        float acc = nb2[o];
        for (int k = 0; k < 64; ++k) acc += sh_h[i * 65 + k] * nw2[k * 32 + o];
        sh_f2[i * 33 + o] = acc;
    }
    __syncthreads();

    // ---- C: norms, class-match row/col counts ----
    if (tid < 64) {
        float acc = 0.0f;
        for (int k = 0; k < 32; ++k) { float v = sh_f1[tid * 33 + k]; acc += v * v; }
        sh_n1[tid] = fmaxf(sqrtf(acc), 1e-8f);
    } else if (tid < 128) {
        int i = tid - 64; float acc = 0.0f;
        for (int k = 0; k < 32; ++k) { float v = sh_f2[i * 33 + k]; acc += v * v; }
        sh_n2[i] = fmaxf(sqrtf(acc), 1e-8f);
    } else if (tid < 192) {
        int i = tid - 128; float s = 0.0f;
        for (int j = 0; j < 64; ++j) s += (sh_cls1[i] == sh_cls2[j]) ? 1.0f : 0.0f;
        sh_R[i] = s;
    } else if (tid < 256) {
        int j = tid - 192; float s = 0.0f;
        for (int i = 0; i < 64; ++i) s += (sh_cls1[i] == sh_cls2[j]) ? 1.0f : 0.0f;
        sh_C[j] = s;
    }
    __syncthreads();
    if (tid == 0) { float s = 0.0f; for (int r = 0; r < 64; ++r) s += sh_R[r]; sh_T[0] = s; }
    __syncthreads();

    // ---- D: dinv (into sh_h alias) and x0 = node_aff ----
    #pragma unroll
    for (int p = 0; p < 4; ++p) {
        int a = tid + (p << 10);
        int i = a >> 6, j = a & 63;
        float mm = (sh_cls1[i] == sh_cls2[j]) ? 1.0f : 0.0f;
        float rs = (mm != 0.0f) ? (sh_T[0] - sh_R[i] - sh_C[j] + 3.0f) : 1.0f;
        dinv[a] = 1.0f / sqrtf(rs);
        float dot = 0.0f;
        for (int k = 0; k < 32; ++k) dot += sh_f1[i * 33 + k] * sh_f2[j * 33 + k];
        float cosv = dot / (sh_n1[i] * sh_n2[j]);
        x0[a] = (mm != 0.0f) ? sqrtf(sh_cf1[i] * sh_cf2[j]) * cosv : 0.0f;
    }
    __syncthreads();

    // ---- E: direction vectors a_*[o] and scalar coefficients ----
    if (tid < 16) {
        int o = tid;
        float ax = 0, av = 0, as_ = 0, aw = 0, au = 0, ae = 0, a1 = 0;
        for (int k = 0; k < 16; ++k) {
            float s0k = sw0[k], c0k = cw0[k], b0k = sb0[k] + cb0[k];
            float s1ko = sw1[k * 16 + o], c1ko = cw1[k * 16 + o];
            ax  += s0k * s1ko;
            av  += c0k * s1ko + s0k * c1ko;
            as_ += s1ko;
            aw  += c0k * c1ko;
            au  += c1ko;
            ae  += b0k * c1ko;
            a1  += b0k * s1ko;
        }
        a1 += sb1[o] + cb1[o];
        sh_avec[0 * 16 + o] = ax;  sh_avec[1 * 16 + o] = av; sh_avec[2 * 16 + o] = as_;
        sh_avec[3 * 16 + o] = aw;  sh_avec[4 * 16 + o] = au; sh_avec[5 * 16 + o] = ae;
        sh_avec[6 * 16 + o] = a1;
    }
    __syncthreads();
    if (tid < 18) {
        float c = 0.0f;
        if (tid == 0)      { for (int k = 0; k < 16; ++k) c += sw0[k] * kw0[k]; }
        else if (tid == 1) { for (int k = 0; k < 16; ++k) c += cw0[k] * kw0[k]; }
        else if (tid == 2) { for (int k = 0; k < 16; ++k) c += (sb0[k] + cb0[k]) * kw0[k]; c += kb0[0]; }
        else if (tid < 10) { int v = tid - 3;
            for (int o = 0; o < 16; ++o) c += sh_avec[v * 16 + o] * kw1[o];
            if (v == 6) c += kb1[0];
        } else if (tid < 17) { int v = tid - 10;
            for (int o = 0; o < 16; ++o) c += sh_avec[v * 16 + o] * fcw[o];
            if (v == 6) c += fcb[0];
        } else { for (int o = 0; o < 16; ++o) c += fcw[o]; }
        sh_coef[tid] = c;
    }
    __syncthreads();

    // ---- F: v0 = normA @ x0 ----
    norma_matvec(x0, v0, nullptr, nullptr, 0.0f, 0.0f,
                 dinv, sh_cls1, sh_cls2, sh_WR, sh_WC, sh_pcol, sh_W, tid);

    // ---- G: t0 -> sinkhorn -> s0; init tacc (t1) and sacc (scores) ----
    {
        float c0 = sh_coef[0], c1 = sh_coef[1], c2 = sh_coef[2];
        #pragma unroll
        for (int p = 0; p < 4; ++p) {
            int a = tid + (p << 10);
            float t = c0 * x0[a] + c1 * v0[a] + c2;
            sh_sk[(a >> 6) * 65 + (a & 63)] = t / TAU_F;
        }
    }
    sinkhorn_inplace(sh_sk, tid);
    {
        float ctx = sh_coef[3], ctv = sh_coef[4], cts = sh_coef[5], ct1 = sh_coef[9];
        float csx = sh_coef[10], csv = sh_coef[11], css = sh_coef[12], cs1 = sh_coef[16];
        #pragma unroll
        for (int p = 0; p < 4; ++p) {
            int a = tid + (p << 10);
            float sv = expf(sh_sk[(a >> 6) * 65 + (a & 63)]);
            s0[a] = sv;
            float xa = x0[a], va = v0[a];
            tacc[a] = ctx * xa + ctv * va + cts * sv + ct1;
            sacc[a] = csx * xa + csv * va + css * sv + cs1;
        }
    }
    __syncthreads();

    // ---- H: accumulate w0 = normA v0, u0 = normA s0, e0 = normA 1 ----
    norma_matvec(v0, nullptr, tacc, sacc, sh_coef[6], sh_coef[13],
                 dinv, sh_cls1, sh_cls2, sh_WR, sh_WC, sh_pcol, sh_W, tid);
    norma_matvec(s0, nullptr, tacc, sacc, sh_coef[7], sh_coef[14],
                 dinv, sh_cls1, sh_cls2, sh_WR, sh_WC, sh_pcol, sh_W, tid);
    norma_matvec(nullptr, nullptr, tacc, sacc, sh_coef[8], sh_coef[15],
                 dinv, sh_cls1, sh_cls2, sh_WR, sh_WC, sh_pcol, sh_W, tid);

    // ---- I: t1 -> sinkhorn -> s1; finish scores ----
    #pragma unroll
    for (int p = 0; p < 4; ++p) {
        int a = tid + (p << 10);
        sh_sk[(a >> 6) * 65 + (a & 63)] = tacc[a] / TAU_F;
    }
    sinkhorn_inplace(sh_sk, tid);
    {
        float csk1 = sh_coef[17];
        #pragma unroll
        for (int p = 0; p < 4; ++p) {
            int a = tid + (p << 10);
            sacc[a] += csk1 * expf(sh_sk[(a >> 6) * 65 + (a & 63)]);
        }
    }
    __syncthreads();

    // ---- J: s[i,j] = scores[j*64+i]; final sinkhorn; output ----
    #pragma unroll
    for (int p = 0; p < 4; ++p) {
        int idx = tid + (p << 10);
        int i = idx >> 6, j = idx & 63;
        sh_sk[i * 65 + j] = sacc[j * 64 + i] / TAU_F;
    }
    sinkhorn_inplace(sh_sk, tid);
    #pragma unroll
    for (int p = 0; p < 4; ++p) {
        int idx = tid + (p << 10);
        int i = idx >> 6, j = idx & 63;
        out[idx] = expf(sh_sk[i * 65 + j]);
    }
}

extern "C" void kernel_launch(void* const* d_in, const int* in_sizes, int n_in,
                              void* d_out, int out_size, void* d_ws, size_t ws_size,
                              hipStream_t stream) {
    const float* ego = (const float*)d_in[0];
    const float* cav = (const float*)d_in[1];
    const float* nw1 = (const float*)d_in[2];
    const float* nb1 = (const float*)d_in[3];
    const float* nw2 = (const float*)d_in[4];
    const float* nb2 = (const float*)d_in[5];
    // d_in[6..9] = edge MLP weights: dead code (edge values only feed (K!=0) pattern)
    const float* sw0 = (const float*)d_in[10];
    const float* sb0 = (const float*)d_in[11];
    const float* cw0 = (const float*)d_in[12];
    const float* cb0 = (const float*)d_in[13];
    const float* kw0 = (const float*)d_in[14];
    const float* kb0 = (const float*)d_in[15];
    const float* sw1 = (const float*)d_in[16];
    const float* sb1 = (const float*)d_in[17];
    const float* cw1 = (const float*)d_in[18];
    const float* cb1 = (const float*)d_in[19];
    const float* kw1 = (const float*)d_in[20];
    const float* kb1 = (const float*)d_in[21];
    const float* fcw = (const float*)d_in[22];
    const float* fcb = (const float*)d_in[23];

    gcn_match_kernel<<<dim3(1), dim3(1024), 0, stream>>>(
        ego, cav, nw1, nb1, nw2, nb2,
        sw0, sb0, cw0, cb0, kw0, kb0,
        sw1, sb1, cw1, cb1, kw1, kb1,
        fcw, fcb, (float*)d_ws, (float*)d_out);
}

// Round 2
// 160.653 us; speedup vs baseline: 1.7320x; 1.7320x over previous
//
#include <hip/hip_runtime.h>
#include <math.h>

// GCN graph-matching net, restructured (see R0 notes):
//  - K off-diag values only used via (K != 0) -> class-match pattern; edge MLPs dead.
//  - normA @ u collapses to O(N) inclusion-exclusion.
//  - x stays rank<=7; sinkhorn inputs / scores are scalar combos of 5 N-vectors (global ws).
// R1 changes:
//  - sinkhorn: 16 threads/line, 4 elems in regs, DPP butterfly reductions (VALU pipe,
//    zero LDS shuffle traffic), __expf/__logf. LDS ops per iter: 896 -> 128, conflict-free.
//  - H-phase 3 matvecs -> 2 via linearity of normA.
//  - nw2 staged in LDS (reusing sh_sk) for MLP second layer.

#define TAU_F 0.05f

// DPP cross-lane move within rows of 16 lanes (VALU pipe, no LDS traffic).
template<int CTRL>
__device__ __forceinline__ float dppf(float x) {
    int xi = __float_as_int(x);
    int r  = __builtin_amdgcn_update_dpp(xi, xi, CTRL, 0xF, 0xF, false);
    return __int_as_float(r);
}
// Butterfly over 16 consecutive lanes: xor1 (quad_perm[1,0,3,2]=0xB1),
// xor2 (quad_perm[2,3,0,1]=0x4E), xor7 (row_half_mirror=0x141), xor15 (row_mirror=0x140).
__device__ __forceinline__ float red16_max(float v) {
    v = fmaxf(v, dppf<0xB1>(v));
    v = fmaxf(v, dppf<0x4E>(v));
    v = fmaxf(v, dppf<0x141>(v));
    v = fmaxf(v, dppf<0x140>(v));
    return v;
}
__device__ __forceinline__ float red16_sum(float v) {
    v += dppf<0xB1>(v);
    v += dppf<0x4E>(v);
    v += dppf<0x141>(v);
    v += dppf<0x140>(v);
    return v;
}
__device__ __forceinline__ float wave_sum64(float v) {
    #pragma unroll
    for (int off = 32; off > 0; off >>= 1) v += __shfl_xor(v, off, 64);
    return v;
}

// 20 alternating row/col logsumexp normalizations on 64x64 (stride-65) LDS matrix.
// Thread t owns line (t>>4), elements 4*(t&15)..+3. Each thread reads/writes only its
// own 4 elements -> one barrier per iteration (orientation flip). Leaves log-values.
__device__ void sinkhorn_inplace(float* sk, int tid) {
    const int line = tid >> 4;   // 0..63
    const int seg  = tid & 15;   // 0..15
    for (int it = 0; it < 20; ++it) {
        __syncthreads();
        float v0, v1, v2, v3;
        if ((it & 1) == 0) {                       // rows: line = row
            const float* p = sk + line * 65 + seg * 4;
            v0 = p[0]; v1 = p[1]; v2 = p[2]; v3 = p[3];
            float mx = red16_max(fmaxf(fmaxf(v0, v1), fmaxf(v2, v3)));
            float s  = red16_sum(__expf(v0 - mx) + __expf(v1 - mx) +
                                 __expf(v2 - mx) + __expf(v3 - mx));
            float lse = __logf(s) + mx;
            float* q = sk + line * 65 + seg * 4;
            q[0] = v0 - lse; q[1] = v1 - lse; q[2] = v2 - lse; q[3] = v3 - lse;
        } else {                                   // cols: line = col
            const float* p = sk + (seg * 4) * 65 + line;
            v0 = p[0]; v1 = p[65]; v2 = p[130]; v3 = p[195];
            float mx = red16_max(fmaxf(fmaxf(v0, v1), fmaxf(v2, v3)));
            float s  = red16_sum(__expf(v0 - mx) + __expf(v1 - mx) +
                                 __expf(v2 - mx) + __expf(v3 - mx));
            float lse = __logf(s) + mx;
            float* q = sk + (seg * 4) * 65 + line;
            q[0] = v0 - lse; q[65] = v1 - lse; q[130] = v2 - lse; q[195] = v3 - lse;
        }
    }
    __syncthreads();
}

// o = normA @ (ca*ua + cb*ub + cc). If outv!=nullptr write o there, else acc[a] += o.
// All 1024 threads must call.
__device__ void norma_matvec(const float* ua, const float* ub, float ca, float cb, float cc,
                             float* outv, float* acc,
                             const float* dinv, const float* cls1, const float* cls2,
                             float* WR, float* WC, float* pcol, float* Wtot, int tid) {
    const int wave = tid >> 6, lane = tid & 63;
    // row sums of z = m .* dinv .* u  (wave per row, 4 rows/wave)
    #pragma unroll
    for (int p = 0; p < 4; ++p) {
        int r = wave + (p << 4);
        int a = r * 64 + lane;
        float mm = (cls1[r] == cls2[lane]) ? 1.0f : 0.0f;
        float uv = ca * ua[a] + cb * ub[a] + cc;
        float z = mm * dinv[a] * uv;
        float s = wave_sum64(z);
        if (lane == 0) WR[r] = s;
    }
    // column partials (coalesced reads, padded LDS partials)
    {
        int j = tid & 63, w = tid >> 6;
        float accv = 0.0f;
        #pragma unroll
        for (int k = 0; k < 4; ++k) {
            int a = tid + (k << 10);
            int i = a >> 6;
            float mm = (cls1[i] == cls2[j]) ? 1.0f : 0.0f;
            float uv = ca * ua[a] + cb * ub[a] + cc;
            accv += mm * dinv[a] * uv;
        }
        pcol[w * 65 + j] = accv;
    }
    __syncthreads();
    if (tid < 64) {
        float s = 0.0f;
        #pragma unroll
        for (int w = 0; w < 16; ++w) s += pcol[w * 65 + tid];
        WC[tid] = s;
    } else if (tid == 64) {
        float s = 0.0f;
        for (int r = 0; r < 64; ++r) s += WR[r];
        Wtot[0] = s;
    }
    __syncthreads();
    const float Wt = Wtot[0];
    #pragma unroll
    for (int p = 0; p < 4; ++p) {
        int a = tid + (p << 10);
        int i = a >> 6, j = a & 63;
        float mm = (cls1[i] == cls2[j]) ? 1.0f : 0.0f;
        float d = dinv[a];
        float uv = ca * ua[a] + cb * ub[a] + cc;
        float za = mm * d * uv;
        float o = d * ((1.0f + mm) * d * uv + mm * (Wt - WR[i] - WC[j] + za));
        if (outv) outv[a] = o;
        else acc[a] += o;
    }
    __syncthreads();  // protect WR/WC/pcol for next call
}

extern "C" __global__ __launch_bounds__(1024)
void gcn_match_kernel(const float* ego, const float* cav,
                      const float* nw1, const float* nb1, const float* nw2, const float* nb2,
                      const float* sw0, const float* sb0, const float* cw0, const float* cb0,
                      const float* kw0, const float* kb0,
                      const float* sw1, const float* sb1, const float* cw1, const float* cb1,
                      const float* kw1, const float* kb1,
                      const float* fcw, const float* fcb,
                      float* ws, float* out) {
    __shared__ float sh_h[64 * 65];      // MLP hidden; later aliased as dinv (4096 floats)
    __shared__ float sh_f1[64 * 33];
    __shared__ float sh_f2[64 * 33];
    __shared__ float sh_sk[64 * 65];     // nw2 staging early; sinkhorn matrix later
    __shared__ float sh_pcol[16 * 65];
    __shared__ float sh_WR[64], sh_WC[64];
    __shared__ float sh_R[64], sh_C[64];
    __shared__ float sh_cls1[64], sh_cls2[64], sh_cf1[64], sh_cf2[64];
    __shared__ float sh_n1[64], sh_n2[64];
    __shared__ float sh_avec[7 * 16];
    __shared__ float sh_coef[18];
    __shared__ float sh_W[1], sh_T[1];

    const int tid = threadIdx.x;
    float* dinv = sh_h;  // alias: sh_h free after f1/f2 are built

    float* x0   = ws;
    float* v0   = ws + 4096;
    float* s0   = ws + 8192;
    float* tacc = ws + 12288;
    float* sacc = ws + 16384;

    // ---- A: per-node cls/conf; stage nw2 into sh_sk; ego hidden layer ----
    if (tid < 64) { sh_cls1[tid] = ego[tid * 8 + 6]; sh_cf1[tid] = ego[tid * 8 + 7]; }
    else if (tid < 128) { int j = tid - 64; sh_cls2[j] = cav[j * 8 + 6]; sh_cf2[j] = cav[j * 8 + 7]; }
    #pragma unroll
    for (int t = tid; t < 2048; t += 1024) sh_sk[t] = nw2[t];
    #pragma unroll
    for (int p = 0; p < 4; ++p) {  // ego hidden
        int item = tid + (p << 10);
        int i = item >> 6, k = item & 63;
        float acc = nb1[k];
        #pragma unroll
        for (int f = 0; f < 5; ++f) acc += ego[i * 8 + 1 + f] * nw1[f * 64 + k];
        sh_h[i * 65 + k] = fmaxf(acc, 0.0f);
    }
    __syncthreads();

    // ---- B: f1 = h @ W2 + b2; then cav hidden; f2 ----
    #pragma unroll
    for (int p = 0; p < 2; ++p) {  // f1
        int item = tid + (p << 10);
        int i = item >> 5, o = item & 31;
        float acc = nb2[o];
        for (int k = 0; k < 64; ++k) acc += sh_h[i * 65 + k] * sh_sk[k * 32 + o];
        sh_f1[i * 33 + o] = acc;
    }
    __syncthreads();
    #pragma unroll
    for (int p = 0; p < 4; ++p) {  // cav hidden
        int item = tid + (p << 10);
        int i = item >> 6, k = item & 63;
        float acc = nb1[k];
        #pragma unroll
        for (int f = 0; f < 5; ++f) acc += cav[i * 8 + 1 + f] * nw1[f * 64 + k];
        sh_h[i * 65 + k] = fmaxf(acc, 0.0f);
    }
    __syncthreads();
    #pragma unroll
    for (int p = 0; p < 2; ++p) {  // f2
        int item = tid + (p << 10);
        int i = item >> 5, o = item & 31;
        float acc = nb2[o];
        for (int k = 0; k < 64; ++k) acc += sh_h[i * 65 + k] * sh_sk[k * 32 + o];
        sh_f2[i * 33 + o] = acc;
    }
    __syncthreads();

    // ---- C: norms, class-match row/col counts ----
    if (tid < 64) {
        float acc = 0.0f;
        for (int k = 0; k < 32; ++k) { float v = sh_f1[tid * 33 + k]; acc += v * v; }
        sh_n1[tid] = fmaxf(sqrtf(acc), 1e-8f);
    } else if (tid < 128) {
        int i = tid - 64; float acc = 0.0f;
        for (int k = 0; k < 32; ++k) { float v = sh_f2[i * 33 + k]; acc += v * v; }
        sh_n2[i] = fmaxf(sqrtf(acc), 1e-8f);
    } else if (tid < 192) {
        int i = tid - 128; float s = 0.0f;
        for (int j = 0; j < 64; ++j) s += (sh_cls1[i] == sh_cls2[j]) ? 1.0f : 0.0f;
        sh_R[i] = s;
    } else if (tid < 256) {
        int j = tid - 192; float s = 0.0f;
        for (int i = 0; i < 64; ++i) s += (sh_cls1[i] == sh_cls2[j]) ? 1.0f : 0.0f;
        sh_C[j] = s;
    }
    __syncthreads();
    if (tid == 0) { float s = 0.0f; for (int r = 0; r < 64; ++r) s += sh_R[r]; sh_T[0] = s; }
    __syncthreads();

    // ---- D: dinv (into sh_h alias) and x0 = node_aff ----
    #pragma unroll
    for (int p = 0; p < 4; ++p) {
        int a = tid + (p << 10);
        int i = a >> 6, j = a & 63;
        float mm = (sh_cls1[i] == sh_cls2[j]) ? 1.0f : 0.0f;
        float rs = (mm != 0.0f) ? (sh_T[0] - sh_R[i] - sh_C[j] + 3.0f) : 1.0f;
        dinv[a] = 1.0f / sqrtf(rs);
        float dot = 0.0f;
        for (int k = 0; k < 32; ++k) dot += sh_f1[i * 33 + k] * sh_f2[j * 33 + k];
        float cosv = dot / (sh_n1[i] * sh_n2[j]);
        x0[a] = (mm != 0.0f) ? sqrtf(sh_cf1[i] * sh_cf2[j]) * cosv : 0.0f;
    }
    __syncthreads();

    // ---- E: direction vectors a_*[o] and scalar coefficients ----
    if (tid < 16) {
        int o = tid;
        float ax = 0, av = 0, as_ = 0, aw = 0, au = 0, ae = 0, a1 = 0;
        for (int k = 0; k < 16; ++k) {
            float s0k = sw0[k], c0k = cw0[k], b0k = sb0[k] + cb0[k];
            float s1ko = sw1[k * 16 + o], c1ko = cw1[k * 16 + o];
            ax  += s0k * s1ko;
            av  += c0k * s1ko + s0k * c1ko;
            as_ += s1ko;
            aw  += c0k * c1ko;
            au  += c1ko;
            ae  += b0k * c1ko;
            a1  += b0k * s1ko;
        }
        a1 += sb1[o] + cb1[o];
        sh_avec[0 * 16 + o] = ax;  sh_avec[1 * 16 + o] = av; sh_avec[2 * 16 + o] = as_;
        sh_avec[3 * 16 + o] = aw;  sh_avec[4 * 16 + o] = au; sh_avec[5 * 16 + o] = ae;
        sh_avec[6 * 16 + o] = a1;
    }
    __syncthreads();
    if (tid < 18) {
        float c = 0.0f;
        if (tid == 0)      { for (int k = 0; k < 16; ++k) c += sw0[k] * kw0[k]; }
        else if (tid == 1) { for (int k = 0; k < 16; ++k) c += cw0[k] * kw0[k]; }
        else if (tid == 2) { for (int k = 0; k < 16; ++k) c += (sb0[k] + cb0[k]) * kw0[k]; c += kb0[0]; }
        else if (tid < 10) { int v = tid - 3;
            for (int o = 0; o < 16; ++o) c += sh_avec[v * 16 + o] * kw1[o];
            if (v == 6) c += kb1[0];
        } else if (tid < 17) { int v = tid - 10;
            for (int o = 0; o < 16; ++o) c += sh_avec[v * 16 + o] * fcw[o];
            if (v == 6) c += fcb[0];
        } else { for (int o = 0; o < 16; ++o) c += fcw[o]; }
        sh_coef[tid] = c;
    }
    __syncthreads();

    // ---- F: v0 = normA @ x0 ----
    norma_matvec(x0, x0, 1.0f, 0.0f, 0.0f, v0, nullptr,
                 dinv, sh_cls1, sh_cls2, sh_WR, sh_WC, sh_pcol, sh_W, tid);

    // ---- G: t0 -> sinkhorn -> s0; init tacc (t1) and sacc (scores) ----
    {
        float c0 = sh_coef[0], c1 = sh_coef[1], c2 = sh_coef[2];
        #pragma unroll
        for (int p = 0; p < 4; ++p) {
            int a = tid + (p << 10);
            float t = c0 * x0[a] + c1 * v0[a] + c2;
            sh_sk[(a >> 6) * 65 + (a & 63)] = t / TAU_F;
        }
    }
    sinkhorn_inplace(sh_sk, tid);
    {
        float ctx = sh_coef[3], ctv = sh_coef[4], cts = sh_coef[5], ct1 = sh_coef[9];
        float csx = sh_coef[10], csv = sh_coef[11], css = sh_coef[12], cs1 = sh_coef[16];
        #pragma unroll
        for (int p = 0; p < 4; ++p) {
            int a = tid + (p << 10);
            float sv = __expf(sh_sk[(a >> 6) * 65 + (a & 63)]);
            s0[a] = sv;
            float xa = x0[a], va = v0[a];
            tacc[a] = ctx * xa + ctv * va + cts * sv + ct1;
            sacc[a] = csx * xa + csv * va + css * sv + cs1;
        }
    }
    __syncthreads();

    // ---- H: tacc += normA(c6*v0 + c7*s0 + c8); sacc += normA(c13*v0 + c14*s0 + c15) ----
    norma_matvec(v0, s0, sh_coef[6], sh_coef[7], sh_coef[8], nullptr, tacc,
                 dinv, sh_cls1, sh_cls2, sh_WR, sh_WC, sh_pcol, sh_W, tid);
    norma_matvec(v0, s0, sh_coef[13], sh_coef[14], sh_coef[15], nullptr, sacc,
                 dinv, sh_cls1, sh_cls2, sh_WR, sh_WC, sh_pcol, sh_W, tid);

    // ---- I: t1 -> sinkhorn -> s1; finish scores ----
    #pragma unroll
    for (int p = 0; p < 4; ++p) {
        int a = tid + (p << 10);
        sh_sk[(a >> 6) * 65 + (a & 63)] = tacc[a] / TAU_F;
    }
    sinkhorn_inplace(sh_sk, tid);
    {
        float csk1 = sh_coef[17];
        #pragma unroll
        for (int p = 0; p < 4; ++p) {
            int a = tid + (p << 10);
            sacc[a] += csk1 * __expf(sh_sk[(a >> 6) * 65 + (a & 63)]);
        }
    }
    __syncthreads();

    // ---- J: s[i,j] = scores[j*64+i]; final sinkhorn; output ----
    #pragma unroll
    for (int p = 0; p < 4; ++p) {
        int idx = tid + (p << 10);
        int i = idx >> 6, j = idx & 63;
        sh_sk[i * 65 + j] = sacc[j * 64 + i] / TAU_F;
    }
    sinkhorn_inplace(sh_sk, tid);
    #pragma unroll
    for (int p = 0; p < 4; ++p) {
        int idx = tid + (p << 10);
        int i = idx >> 6, j = idx & 63;
        out[idx] = __expf(sh_sk[i * 65 + j]);
    }
}

extern "C" void kernel_launch(void* const* d_in, const int* in_sizes, int n_in,
                              void* d_out, int out_size, void* d_ws, size_t ws_size,
                              hipStream_t stream) {
    const float* ego = (const float*)d_in[0];
    const float* cav = (const float*)d_in[1];
    const float* nw1 = (const float*)d_in[2];
    const float* nb1 = (const float*)d_in[3];
    const float* nw2 = (const float*)d_in[4];
    const float* nb2 = (const float*)d_in[5];
    // d_in[6..9] = edge MLP weights: dead code (edge values only feed (K!=0) pattern)
    const float* sw0 = (const float*)d_in[10];
    const float* sb0 = (const float*)d_in[11];
    const float* cw0 = (const float*)d_in[12];
    const float* cb0 = (const float*)d_in[13];
    const float* kw0 = (const float*)d_in[14];
    const float* kb0 = (const float*)d_in[15];
    const float* sw1 = (const float*)d_in[16];
    const float* sb1 = (const float*)d_in[17];
    const float* cw1 = (const float*)d_in[18];
    const float* cb1 = (const float*)d_in[19];
    const float* kw1 = (const float*)d_in[20];
    const float* kb1 = (const float*)d_in[21];
    const float* fcw = (const float*)d_in[22];
    const float* fcb = (const float*)d_in[23];

    gcn_match_kernel<<<dim3(1), dim3(1024), 0, stream>>>(
        ego, cav, nw1, nb1, nw2, nb2,
        sw0, sb0, cw0, cb0, kw0, kb0,
        sw1, sb1, cw1, cb1, kw1, kb1,
        fcw, fcb, (float*)d_ws, (float*)d_out);
}

// Round 3
// 157.043 us; speedup vs baseline: 1.7718x; 1.0230x over previous
//
#include <hip/hip_runtime.h>
#include <math.h>

// GCN graph-matching net. Key reductions (verified R0/R1, absmax ~1e-13):
//  - K off-diag values only used via (K != 0) -> class-match pattern m[i,j]=(cls1==cls2).
//  - normA @ u collapses to O(N) inclusion-exclusion with row/col sums.
//  - x stays rank<=7; all sinkhorn inputs / scores are scalar combos of a few N-vectors.
// R2: everything register-resident. Sinkhorn in R/C-scaling form: log_s = t - R_i - C_j,
//   R_i = lse_j(t-C), C_j = lse_i(t-R); t held in regs in BOTH orientations (one LDS
//   transpose per sinkhorn). N-vectors in Q-layout regs (row=tid>>4, cols 4*(tid&15)+k).
//   Matvecs: DPP 16-lane row sums + shfl_xor col partials + small LDS tables; dual-basis
//   fused pass for layer-1 conv; normA*ones precomputed. No global scratch at all.

#define TAU_INV 20.0f

// DPP cross-lane move within 16-lane rows (VALU pipe).
template<int CTRL>
__device__ __forceinline__ float dppf(float x) {
    int xi = __float_as_int(x);
    int r  = __builtin_amdgcn_update_dpp(xi, xi, CTRL, 0xF, 0xF, false);
    return __int_as_float(r);
}
__device__ __forceinline__ float red16_max(float v) {
    v = fmaxf(v, dppf<0xB1>(v));    // xor1
    v = fmaxf(v, dppf<0x4E>(v));    // xor2
    v = fmaxf(v, dppf<0x141>(v));   // xor7 row_half_mirror (with xor1,2 => covers 4)
    v = fmaxf(v, dppf<0x140>(v));   // xor15 row_mirror
    return v;
}
__device__ __forceinline__ float red16_sum(float v) {
    v += dppf<0xB1>(v);
    v += dppf<0x4E>(v);
    v += dppf<0x141>(v);
    v += dppf<0x140>(v);
    return v;
}

// 20 alternating row/col steps. tq: own 4 elems of t (row g=tid>>4, cols 4s+k);
// tt: own 4 elems of t^T (col g, rows 4s+k). R,C in LDS; C must be zeroed before entry
// (behind a barrier). One barrier per step. Leaves final R,C.
__device__ void sinkhorn_rc(const float* tq, const float* tt, int tid, float* R, float* C) {
    const int g = tid >> 4, s = tid & 15;
    for (int it = 0; it < 20; ++it) {
        if ((it & 1) == 0) {          // rows: R_g = lse_j(t[g][j] - C[j])
            float z0 = tq[0] - C[4*s+0], z1 = tq[1] - C[4*s+1];
            float z2 = tq[2] - C[4*s+2], z3 = tq[3] - C[4*s+3];
            float m = red16_max(fmaxf(fmaxf(z0, z1), fmaxf(z2, z3)));
            float sum = red16_sum(__expf(z0-m) + __expf(z1-m) + __expf(z2-m) + __expf(z3-m));
            if (s == 0) R[g] = __logf(sum) + m;
        } else {                      // cols: C_g = lse_i(t[i][g] - R[i])
            float z0 = tt[0] - R[4*s+0], z1 = tt[1] - R[4*s+1];
            float z2 = tt[2] - R[4*s+2], z3 = tt[3] - R[4*s+3];
            float m = red16_max(fmaxf(fmaxf(z0, z1), fmaxf(z2, z3)));
            float sum = red16_sum(__expf(z0-m) + __expf(z1-m) + __expf(z2-m) + __expf(z3-m));
            if (s == 0) C[g] = __logf(sum) + m;
        }
        __syncthreads();
    }
}

// Dual-basis normA matvec on register quads. o_t = d*((1+m)*d*u_t + m*(W_t - WR_t[i] - WC_t[j] + z_t)).
// pwc: 2048-float LDS scratch. scW: {W1,W2} slots. 3 internal barriers (incl. trailing).
__device__ void matvec_dual(const float* u1, const float* u2,
                            const float* mmq, const float* dq,
                            float* o1, float* o2, int tid,
                            float* WR1, float* WR2, float* WC1, float* WC2,
                            float* pwc, float* scW) {
    const int r = tid >> 4, s = tid & 15, lane = tid & 63, w = tid >> 6;
    float z1[4], z2[4];
    float rs1 = 0.0f, rs2 = 0.0f;
    #pragma unroll
    for (int k = 0; k < 4; ++k) {
        float md = mmq[k] * dq[k];
        z1[k] = md * u1[k];
        z2[k] = md * u2[k];
        rs1 += z1[k]; rs2 += z2[k];
    }
    rs1 = red16_sum(rs1); rs2 = red16_sum(rs2);
    if (s == 0) { WR1[r] = rs1; WR2[r] = rs2; }
    // per-wave column partials: sum over the wave's 4 rows (lanes s, s+16, s+32, s+48)
    float p1[4], p2[4];
    #pragma unroll
    for (int k = 0; k < 4; ++k) {
        float v = z1[k]; v += __shfl_xor(v, 16); v += __shfl_xor(v, 32); p1[k] = v;
        float u = z2[k]; u += __shfl_xor(u, 16); u += __shfl_xor(u, 32); p2[k] = u;
    }
    if (lane < 16) {
        ((float4*)pwc)[w * 16 + s]        = make_float4(p1[0], p1[1], p1[2], p1[3]);
        ((float4*)(pwc + 1024))[w * 16 + s] = make_float4(p2[0], p2[1], p2[2], p2[3]);
    }
    __syncthreads();
    if (tid < 64) {
        float c1 = 0.0f, c2 = 0.0f;
        #pragma unroll
        for (int ww = 0; ww < 16; ++ww) {
            c1 += pwc[ww * 64 + tid];
            c2 += pwc[1024 + ww * 64 + tid];
        }
        WC1[tid] = c1; WC2[tid] = c2;
    } else if (tid < 128) {
        float v = WR1[tid - 64];
        #pragma unroll
        for (int off = 32; off > 0; off >>= 1) v += __shfl_xor(v, off);
        if (tid == 64) scW[0] = v;
    } else if (tid < 192) {
        float v = WR2[tid - 128];
        #pragma unroll
        for (int off = 32; off > 0; off >>= 1) v += __shfl_xor(v, off);
        if (tid == 128) scW[1] = v;
    }
    __syncthreads();
    const float W1 = scW[0], W2 = scW[1];
    const float wr1 = WR1[r], wr2 = WR2[r];
    #pragma unroll
    for (int k = 0; k < 4; ++k) {
        int j = 4 * s + k;
        float d = dq[k], mm = mmq[k];
        o1[k] = d * ((1.0f + mm) * d * u1[k] + mm * (W1 - wr1 - WC1[j] + z1[k]));
        o2[k] = d * ((1.0f + mm) * d * u2[k] + mm * (W2 - wr2 - WC2[j] + z2[k]));
    }
    __syncthreads();  // protect WR/WC/pwc for reuse
}

extern "C" __global__ __launch_bounds__(1024)
void gcn_match_kernel(const float* ego, const float* cav,
                      const float* nw1, const float* nb1, const float* nw2, const float* nb2,
                      const float* sw0, const float* sb0, const float* cw0, const float* cb0,
                      const float* kw0, const float* kb0,
                      const float* sw1, const float* sb1, const float* cw1, const float* cb1,
                      const float* kw1, const float* kb1,
                      const float* fcw, const float* fcb,
                      float* out) {
    __shared__ __align__(16) float sh_big[64 * 65];   // h | t-transpose | pwc(2048) | sacc^T
    __shared__ float sh_nw2[2048];
    __shared__ float sh_f1[64 * 33];
    __shared__ float sh_f2[64 * 33];
    __shared__ float sh_nw1[320];
    __shared__ __align__(16) float sh_ego[512], sh_cav[512];
    __shared__ float sh_nb1[64], sh_nb2[32];
    __shared__ float sh_cls1[64], sh_cls2[64], sh_cf1[64], sh_cf2[64];
    __shared__ float sh_n1[64], sh_n2[64];
    __shared__ float sh_Dr[64], sh_Dc[64];
    __shared__ float sh_R[64], sh_C[64];
    __shared__ float sh_WR1[64], sh_WR2[64], sh_WC1[64], sh_WC2[64];
    __shared__ float sh_avec[7 * 16];
    __shared__ float sh_coef[18];
    __shared__ float sh_sc[4];   // [0]=W1 [1]=W2 [2]=Tdeg

    const int tid = threadIdx.x;
    const int r = tid >> 4, s = tid & 15;

    // ---- P0: stage inputs/weights ----
    if (tid < 128) ((float4*)sh_ego)[tid] = ((const float4*)ego)[tid];
    else if (tid < 256) ((float4*)sh_cav)[tid - 128] = ((const float4*)cav)[tid - 128];
    if (tid < 320) sh_nw1[tid] = nw1[tid];
    if (tid < 64)  sh_nb1[tid] = nb1[tid];
    if (tid < 32)  sh_nb2[tid] = nb2[tid];
    sh_nw2[tid] = nw2[tid];
    sh_nw2[tid + 1024] = nw2[tid + 1024];
    __syncthreads();

    // ---- P1a: cls/conf + ego hidden layer (into sh_big, stride 64) ----
    if (tid < 64) { sh_cls1[tid] = sh_ego[tid * 8 + 6]; sh_cf1[tid] = sh_ego[tid * 8 + 7]; }
    else if (tid < 128) { int j = tid - 64; sh_cls2[j] = sh_cav[j * 8 + 6]; sh_cf2[j] = sh_cav[j * 8 + 7]; }
    #pragma unroll
    for (int p = 0; p < 4; ++p) {
        int item = tid + (p << 10);
        int i = item >> 6, k = item & 63;
        float acc = sh_nb1[k];
        #pragma unroll
        for (int f = 0; f < 5; ++f) acc += sh_ego[i * 8 + 1 + f] * sh_nw1[f * 64 + k];
        sh_big[i * 64 + k] = fmaxf(acc, 0.0f);
    }
    __syncthreads();

    // ---- P1b: f1 = h @ W2 + b2 ----
    {
        int o = tid & 31, i0 = tid >> 5, i1 = i0 + 32;
        float a0 = sh_nb2[o], a1 = sh_nb2[o];
        for (int kk = 0; kk < 64; ++kk) {
            float wv = sh_nw2[kk * 32 + o];
            a0 += sh_big[i0 * 64 + kk] * wv;
            a1 += sh_big[i1 * 64 + kk] * wv;
        }
        sh_f1[i0 * 33 + o] = a0;
        sh_f1[i1 * 33 + o] = a1;
    }
    __syncthreads();

    // ---- P1c: cav hidden ----
    #pragma unroll
    for (int p = 0; p < 4; ++p) {
        int item = tid + (p << 10);
        int i = item >> 6, k = item & 63;
        float acc = sh_nb1[k];
        #pragma unroll
        for (int f = 0; f < 5; ++f) acc += sh_cav[i * 8 + 1 + f] * sh_nw1[f * 64 + k];
        sh_big[i * 64 + k] = fmaxf(acc, 0.0f);
    }
    __syncthreads();

    // ---- P1d: f2 ----
    {
        int o = tid & 31, i0 = tid >> 5, i1 = i0 + 32;
        float a0 = sh_nb2[o], a1 = sh_nb2[o];
        for (int kk = 0; kk < 64; ++kk) {
            float wv = sh_nw2[kk * 32 + o];
            a0 += sh_big[i0 * 64 + kk] * wv;
            a1 += sh_big[i1 * 64 + kk] * wv;
        }
        sh_f2[i0 * 33 + o] = a0;
        sh_f2[i1 * 33 + o] = a1;
    }
    __syncthreads();

    // ---- P2a: norms, degree row/col sums, avec ----
    if (tid < 64) {
        float acc = 0.0f;
        for (int k = 0; k < 32; ++k) { float v = sh_f1[tid * 33 + k]; acc += v * v; }
        sh_n1[tid] = fmaxf(sqrtf(acc), 1e-8f);
    } else if (tid < 128) {
        int i = tid - 64; float acc = 0.0f;
        for (int k = 0; k < 32; ++k) { float v = sh_f2[i * 33 + k]; acc += v * v; }
        sh_n2[i] = fmaxf(sqrtf(acc), 1e-8f);
    } else if (tid < 192) {
        int i = tid - 128; float acc = 0.0f;
        for (int j = 0; j < 64; ++j) acc += (sh_cls1[i] == sh_cls2[j]) ? 1.0f : 0.0f;
        sh_Dr[i] = acc;
    } else if (tid < 256) {
        int j = tid - 192; float acc = 0.0f;
        for (int i = 0; i < 64; ++i) acc += (sh_cls1[i] == sh_cls2[j]) ? 1.0f : 0.0f;
        sh_Dc[j] = acc;
    } else if (tid < 272) {
        int o = tid - 256;
        float ax = 0, av = 0, as_ = 0, aw = 0, au = 0, ae = 0, a1 = 0;
        for (int k = 0; k < 16; ++k) {
            float s0k = sw0[k], c0k = cw0[k], b0k = sb0[k] + cb0[k];
            float s1ko = sw1[k * 16 + o], c1ko = cw1[k * 16 + o];
            ax  += s0k * s1ko;
            av  += c0k * s1ko + s0k * c1ko;
            as_ += s1ko;
            aw  += c0k * c1ko;
            au  += c1ko;
            ae  += b0k * c1ko;
            a1  += b0k * s1ko;
        }
        a1 += sb1[o] + cb1[o];
        sh_avec[0*16+o] = ax; sh_avec[1*16+o] = av; sh_avec[2*16+o] = as_;
        sh_avec[3*16+o] = aw; sh_avec[4*16+o] = au; sh_avec[5*16+o] = ae;
        sh_avec[6*16+o] = a1;
    }
    __syncthreads();

    // ---- P2b: coefficients + total degree ----
    if (tid < 18) {
        float c = 0.0f;
        if (tid == 0)      { for (int k = 0; k < 16; ++k) c += sw0[k] * kw0[k]; }
        else if (tid == 1) { for (int k = 0; k < 16; ++k) c += cw0[k] * kw0[k]; }
        else if (tid == 2) { for (int k = 0; k < 16; ++k) c += (sb0[k] + cb0[k]) * kw0[k]; c += kb0[0]; }
        else if (tid < 10) { int v = tid - 3;
            for (int o = 0; o < 16; ++o) c += sh_avec[v * 16 + o] * kw1[o];
            if (v == 6) c += kb1[0];
        } else if (tid < 17) { int v = tid - 10;
            for (int o = 0; o < 16; ++o) c += sh_avec[v * 16 + o] * fcw[o];
            if (v == 6) c += fcb[0];
        } else { for (int o = 0; o < 16; ++o) c += fcw[o]; }
        sh_coef[tid] = c;
    } else if (tid >= 64 && tid < 128) {
        float v = sh_Dr[tid - 64];
        #pragma unroll
        for (int off = 32; off > 0; off >>= 1) v += __shfl_xor(v, off);
        if (tid == 64) sh_sc[2] = v;
    }
    __syncthreads();

    // ---- P3: per-thread constants (mm, dinv) and x0 quad ----
    const float cls1r = sh_cls1[r];
    const float Tdeg = sh_sc[2], Drr = sh_Dr[r];
    const float n1r = sh_n1[r], cf1r = sh_cf1[r];
    float mmq[4], dq[4], x0[4];
    {
        float dot[4] = {0, 0, 0, 0};
        for (int kk = 0; kk < 32; ++kk) {
            float f1v = sh_f1[r * 33 + kk];
            #pragma unroll
            for (int k = 0; k < 4; ++k) dot[k] += f1v * sh_f2[(4 * s + k) * 33 + kk];
        }
        #pragma unroll
        for (int k = 0; k < 4; ++k) {
            int j = 4 * s + k;
            float mm = (cls1r == sh_cls2[j]) ? 1.0f : 0.0f;
            mmq[k] = mm;
            dq[k] = (mm != 0.0f) ? (1.0f / sqrtf(Tdeg - Drr - sh_Dc[j] + 3.0f)) : 1.0f;
            float cosv = dot[k] / (n1r * sh_n2[j]);
            x0[k] = mm * sqrtf(cf1r * sh_cf2[j]) * cosv;
        }
    }

    // ---- P4: pass A — v0 = normA x0, oe = normA 1 (dual) ----
    float v0[4], oe[4];
    {
        float ones[4] = {1.0f, 1.0f, 1.0f, 1.0f};
        matvec_dual(x0, ones, mmq, dq, v0, oe, tid,
                    sh_WR1, sh_WR2, sh_WC1, sh_WC2, sh_big, sh_sc);
    }

    // ---- P5: t0 -> sinkhorn0 -> s0 ----
    float t0q[4];
    {
        float c0 = sh_coef[0], c1 = sh_coef[1], c2 = sh_coef[2];
        #pragma unroll
        for (int k = 0; k < 4; ++k) t0q[k] = (c0 * x0[k] + c1 * v0[k] + c2) * TAU_INV;
    }
    #pragma unroll
    for (int k = 0; k < 4; ++k) sh_big[r * 65 + 4 * s + k] = t0q[k];
    if (tid < 64) sh_C[tid] = 0.0f;
    __syncthreads();
    float t0t[4];
    #pragma unroll
    for (int k = 0; k < 4; ++k) t0t[k] = sh_big[(4 * s + k) * 65 + r];
    sinkhorn_rc(t0q, t0t, tid, sh_R, sh_C);
    float s0[4];
    {
        float Rr = sh_R[r];
        #pragma unroll
        for (int k = 0; k < 4; ++k) s0[k] = __expf(t0q[k] - Rr - sh_C[4 * s + k]);
    }

    // ---- P6: pass B (dual {v0, s0}) + tacc/sacc combos ----
    float ov[4], os[4];
    matvec_dual(v0, s0, mmq, dq, ov, os, tid,
                sh_WR1, sh_WR2, sh_WC1, sh_WC2, sh_big, sh_sc);
    float tacc[4], sacc[4];
    {
        float ctx = sh_coef[3], ctv = sh_coef[4], cts = sh_coef[5];
        float cw_ = sh_coef[6], cu_ = sh_coef[7], ce_ = sh_coef[8], ct1 = sh_coef[9];
        float csx = sh_coef[10], csv = sh_coef[11], css = sh_coef[12];
        float cw2 = sh_coef[13], cu2 = sh_coef[14], ce2 = sh_coef[15], cs1 = sh_coef[16];
        #pragma unroll
        for (int k = 0; k < 4; ++k) {
            tacc[k] = ctx * x0[k] + ctv * v0[k] + cts * s0[k] + ct1
                    + cw_ * ov[k] + cu_ * os[k] + ce_ * oe[k];
            sacc[k] = csx * x0[k] + csv * v0[k] + css * s0[k] + cs1
                    + cw2 * ov[k] + cu2 * os[k] + ce2 * oe[k];
        }
    }

    // ---- P7: t1 -> sinkhorn1 -> s1; sacc += c17*s1 ----
    float t1q[4];
    #pragma unroll
    for (int k = 0; k < 4; ++k) t1q[k] = tacc[k] * TAU_INV;
    #pragma unroll
    for (int k = 0; k < 4; ++k) sh_big[r * 65 + 4 * s + k] = t1q[k];
    if (tid < 64) sh_C[tid] = 0.0f;
    __syncthreads();
    float t1t[4];
    #pragma unroll
    for (int k = 0; k < 4; ++k) t1t[k] = sh_big[(4 * s + k) * 65 + r];
    sinkhorn_rc(t1q, t1t, tid, sh_R, sh_C);
    {
        float c17 = sh_coef[17];
        float Rr = sh_R[r];
        #pragma unroll
        for (int k = 0; k < 4; ++k) sacc[k] += c17 * __expf(t1q[k] - Rr - sh_C[4 * s + k]);
    }
    __syncthreads();   // all C reads done before P8 zeroes C

    // ---- P8: s = sacc^T; final sinkhorn; output ----
    #pragma unroll
    for (int k = 0; k < 4; ++k) sh_big[r * 65 + 4 * s + k] = sacc[k];
    if (tid < 64) sh_C[tid] = 0.0f;
    __syncthreads();
    float t2q[4], t2t[4];
    #pragma unroll
    for (int k = 0; k < 4; ++k) {
        t2q[k] = sh_big[(4 * s + k) * 65 + r] * TAU_INV;  // s[i][j] = sacc[j*64+i]
        t2t[k] = sacc[k] * TAU_INV;                        // s^T[g][p] = own sacc
    }
    sinkhorn_rc(t2q, t2t, tid, sh_R, sh_C);
    {
        float Rr = sh_R[r];
        float4 o4;
        o4.x = __expf(t2q[0] - Rr - sh_C[4 * s + 0]);
        o4.y = __expf(t2q[1] - Rr - sh_C[4 * s + 1]);
        o4.z = __expf(t2q[2] - Rr - sh_C[4 * s + 2]);
        o4.w = __expf(t2q[3] - Rr - sh_C[4 * s + 3]);
        ((float4*)out)[tid] = o4;   // element a = 4*tid + k
    }
}

extern "C" void kernel_launch(void* const* d_in, const int* in_sizes, int n_in,
                              void* d_out, int out_size, void* d_ws, size_t ws_size,
                              hipStream_t stream) {
    const float* ego = (const float*)d_in[0];
    const float* cav = (const float*)d_in[1];
    const float* nw1 = (const float*)d_in[2];
    const float* nb1 = (const float*)d_in[3];
    const float* nw2 = (const float*)d_in[4];
    const float* nb2 = (const float*)d_in[5];
    // d_in[6..9] = edge MLP weights: dead code (edge values only feed the (K!=0) pattern)
    const float* sw0 = (const float*)d_in[10];
    const float* sb0 = (const float*)d_in[11];
    const float* cw0 = (const float*)d_in[12];
    const float* cb0 = (const float*)d_in[13];
    const float* kw0 = (const float*)d_in[14];
    const float* kb0 = (const float*)d_in[15];
    const float* sw1 = (const float*)d_in[16];
    const float* sb1 = (const float*)d_in[17];
    const float* cw1 = (const float*)d_in[18];
    const float* cb1 = (const float*)d_in[19];
    const float* kw1 = (const float*)d_in[20];
    const float* kb1 = (const float*)d_in[21];
    const float* fcw = (const float*)d_in[22];
    const float* fcb = (const float*)d_in[23];

    gcn_match_kernel<<<dim3(1), dim3(1024), 0, stream>>>(
        ego, cav, nw1, nb1, nw2, nb2,
        sw0, sb0, cw0, cb0, kw0, kb0,
        sw1, sb1, cw1, cb1, kw1, kb1,
        fcw, fcb, (float*)d_out);
}

// Round 4
// 136.452 us; speedup vs baseline: 2.0392x; 1.1509x over previous
//
#include <hip/hip_runtime.h>
#include <math.h>

// GCN graph-matching net. Verified reductions (R0-R2, absmax ~0):
//  - K off-diag values only used via (K != 0) -> class-match pattern; edge MLPs dead.
//  - normA @ u collapses to O(N) inclusion-exclusion; x stays rank<=7.
//  - Sinkhorn in R/C-scaling form: log_s = t - R_i - C_j (t register-resident, both orientations).
// R3: minimize LDS-pipe wave-ops (single-CU LDS pipe is the bottleneck):
//  - j-quad convention: thread (r = tid>>4, s = tid&15) owns cols j = s+16k, k=0..3.
//    Permuted storage for j-indexed vectors: Vq[4s+k] = V[s+16k] -> b128 quad reads.
//  - Hidden MLP: W1/b1 in registers (global coalesced), X rows via broadcast global float4.
//  - f = h@W2+b2: 2 waves per GEMM (waves 0-1: f1, 2-3: f2), b128 W2 reads, norms in-register.
//  - Cosine: 4 waves, b128 reads (stride-1 row mapping -> 2-way banks), one LDS redistribute.
//  - Sinkhorn iter: 1 ds_read_b128 + 1 write per wave per iteration.

#define TAU_INV 20.0f

template<int CTRL>
__device__ __forceinline__ float dppf(float x) {
    int xi = __float_as_int(x);
    int rr = __builtin_amdgcn_update_dpp(xi, xi, CTRL, 0xF, 0xF, false);
    return __int_as_float(rr);
}
__device__ __forceinline__ float red16_max(float v) {
    v = fmaxf(v, dppf<0xB1>(v));    // xor1 (quad_perm)
    v = fmaxf(v, dppf<0x4E>(v));    // xor2
    v = fmaxf(v, dppf<0x141>(v));   // row_half_mirror
    v = fmaxf(v, dppf<0x140>(v));   // row_mirror
    return v;
}
__device__ __forceinline__ float red16_sum(float v) {
    v += dppf<0xB1>(v);
    v += dppf<0x4E>(v);
    v += dppf<0x141>(v);
    v += dppf<0x140>(v);
    return v;
}
__device__ __forceinline__ float quad_sum(float v) {   // sum over lane&3
    v += dppf<0xB1>(v);
    v += dppf<0x4E>(v);
    return v;
}
__device__ __forceinline__ float dot4(const float4 a, const float4 b) {
    return a.x*b.x + a.y*b.y + a.z*b.z + a.w*b.w;
}
__device__ __forceinline__ void fma4(float4& a, float b, const float4 c) {
    a.x += b*c.x; a.y += b*c.y; a.z += b*c.z; a.w += b*c.w;
}
__device__ __forceinline__ void add4(float4& a, const float4 c) {
    a.x += c.x; a.y += c.y; a.z += c.z; a.w += c.w;
}

// 20 alternating row/col lse steps; R/C stored PERMUTED (Vq[4s+k] = V[s+16k]).
// tq: row g=tid>>4, cols j=s+16k; tt: col g, rows i=s+16k. One barrier/step.
__device__ void sinkhorn_rc(const float* tq, const float* tt, int tid, float* Rp, float* Cp) {
    const int g = tid >> 4, s = tid & 15;
    const int wa = 4 * (g & 15) + (g >> 4);   // sigma^-1(g)
    for (int it = 0; it < 20; ++it) {
        if ((it & 1) == 0) {                  // rows: R_g = lse_j(t[g][j] - C[j])
            float4 cq = *(const float4*)(Cp + 4 * s);
            float z0 = tq[0]-cq.x, z1 = tq[1]-cq.y, z2 = tq[2]-cq.z, z3 = tq[3]-cq.w;
            float m  = red16_max(fmaxf(fmaxf(z0, z1), fmaxf(z2, z3)));
            float sm = red16_sum(__expf(z0-m) + __expf(z1-m) + __expf(z2-m) + __expf(z3-m));
            if (s == 0) Rp[wa] = __logf(sm) + m;
        } else {                              // cols: C_g = lse_i(t[i][g] - R[i])
            float4 rq = *(const float4*)(Rp + 4 * s);
            float z0 = tt[0]-rq.x, z1 = tt[1]-rq.y, z2 = tt[2]-rq.z, z3 = tt[3]-rq.w;
            float m  = red16_max(fmaxf(fmaxf(z0, z1), fmaxf(z2, z3)));
            float sm = red16_sum(__expf(z0-m) + __expf(z1-m) + __expf(z2-m) + __expf(z3-m));
            if (s == 0) Cp[wa] = __logf(sm) + m;
        }
        __syncthreads();
    }
}

// Dual normA matvec on register quads (j = s+16k convention). WC stored permuted.
__device__ void matvec_dual(const float* u1, const float* u2,
                            const float* mmq, const float* dq,
                            float* o1, float* o2, int tid,
                            float* WR1, float* WR2, float* WC1p, float* WC2p,
                            float* pwc, float* scW) {
    const int r = tid >> 4, s = tid & 15, lane = tid & 63, w = tid >> 6;
    float z1[4], z2[4];
    float rs1 = 0.0f, rs2 = 0.0f;
    #pragma unroll
    for (int k = 0; k < 4; ++k) {
        float md = mmq[k] * dq[k];
        z1[k] = md * u1[k];
        z2[k] = md * u2[k];
        rs1 += z1[k]; rs2 += z2[k];
    }
    rs1 = red16_sum(rs1); rs2 = red16_sum(rs2);
    if (s == 0) { WR1[r] = rs1; WR2[r] = rs2; }
    float p1[4], p2[4];
    #pragma unroll
    for (int k = 0; k < 4; ++k) {   // col partial over the wave's 4 rows
        float v = z1[k]; v += __shfl_xor(v, 16); v += __shfl_xor(v, 32); p1[k] = v;
        float u = z2[k]; u += __shfl_xor(u, 16); u += __shfl_xor(u, 32); p2[k] = u;
    }
    if (lane < 16) {
        ((float4*)pwc)[w * 16 + s]          = make_float4(p1[0], p1[1], p1[2], p1[3]);
        ((float4*)(pwc + 1024))[w * 16 + s] = make_float4(p2[0], p2[1], p2[2], p2[3]);
    }
    __syncthreads();
    if (tid < 64) {
        float c1 = 0.0f, c2 = 0.0f;
        #pragma unroll
        for (int ww = 0; ww < 16; ++ww) {
            c1 += pwc[ww * 64 + tid];
            c2 += pwc[1024 + ww * 64 + tid];
        }
        WC1p[tid] = c1; WC2p[tid] = c2;      // tid is the q-index -> permuted
    } else if (tid < 128) {
        float v = WR1[tid - 64];
        #pragma unroll
        for (int off = 32; off > 0; off >>= 1) v += __shfl_xor(v, off);
        if (tid == 64) scW[0] = v;
    } else if (tid < 192) {
        float v = WR2[tid - 128];
        #pragma unroll
        for (int off = 32; off > 0; off >>= 1) v += __shfl_xor(v, off);
        if (tid == 128) scW[1] = v;
    }
    __syncthreads();
    const float W1 = scW[0], W2 = scW[1];
    const float wr1 = WR1[r], wr2 = WR2[r];
    float4 wc1 = *(const float4*)(WC1p + 4 * s);
    float4 wc2 = *(const float4*)(WC2p + 4 * s);
    const float wc1a[4] = {wc1.x, wc1.y, wc1.z, wc1.w};
    const float wc2a[4] = {wc2.x, wc2.y, wc2.z, wc2.w};
    #pragma unroll
    for (int k = 0; k < 4; ++k) {
        float d = dq[k], mm = mmq[k];
        o1[k] = d * ((1.0f + mm) * d * u1[k] + mm * (W1 - wr1 - wc1a[k] + z1[k]));
        o2[k] = d * ((1.0f + mm) * d * u2[k] + mm * (W2 - wr2 - wc2a[k] + z2[k]));
    }
    __syncthreads();
}

extern "C" __global__ __launch_bounds__(1024)
void gcn_match_kernel(const float* ego, const float* cav,
                      const float* nw1, const float* nb1, const float* nw2, const float* nb2,
                      const float* sw0, const float* sb0, const float* cw0, const float* cb0,
                      const float* kw0, const float* kb0,
                      const float* sw1, const float* sb1, const float* cw1, const float* cb1,
                      const float* kw1, const float* kb1,
                      const float* fcw, const float* fcb,
                      float* out) {
    __shared__ __align__(16) float sh_h1[64 * 68];   // ego hidden | dots | matvec pwc
    __shared__ __align__(16) float sh_h2[64 * 68];   // cav hidden | sinkhorn transpose buf
    __shared__ __align__(16) float sh_f1[64 * 36];
    __shared__ __align__(16) float sh_f2[64 * 36];
    __shared__ __align__(16) float sh_w2[2048];
    __shared__ __align__(16) float sh_nb2[32];
    __shared__ float sh_cls1[64], sh_cls2[64], sh_cf1[64], sh_cf2[64];
    __shared__ float sh_n1[64], sh_n2[64];
    __shared__ float sh_Dr[64], sh_Dc[64];
    __shared__ __align__(16) float sh_Rp[64], sh_Cp[64];
    __shared__ float sh_WR1[64], sh_WR2[64];
    __shared__ __align__(16) float sh_WC1p[64], sh_WC2p[64];
    __shared__ float sh_avec[7 * 16];
    __shared__ float sh_coef[18];
    __shared__ float sh_sc[4];   // [0],[1]=matvec W totals, [2]=Tdeg

    const int tid  = threadIdx.x;
    const int wave = tid >> 6, lane = tid & 63;
    const int r = tid >> 4, s = tid & 15;

    // ================= B0+B1: staging + hidden layers + cls/cf =================
    if (tid < 512) ((float4*)sh_w2)[tid] = ((const float4*)nw2)[tid];
    if (tid < 32) sh_nb2[tid] = nb2[tid];
    if (tid < 64) { sh_cls1[tid] = ego[tid * 8 + 6]; sh_cf1[tid] = ego[tid * 8 + 7]; }
    else if (tid < 128) { int j = tid - 64; sh_cls2[j] = cav[j * 8 + 6]; sh_cf2[j] = cav[j * 8 + 7]; }
    {
        float w1r[5];
        #pragma unroll
        for (int f = 0; f < 5; ++f) w1r[f] = nw1[f * 64 + lane];
        float b1r = nb1[lane];
        #pragma unroll
        for (int p = 0; p < 4; ++p) {
            int i = wave + (p << 4);
            float4 e0 = ((const float4*)ego)[i * 2];
            float4 e1 = ((const float4*)ego)[i * 2 + 1];
            float a1 = b1r + e0.y*w1r[0] + e0.z*w1r[1] + e0.w*w1r[2] + e1.x*w1r[3] + e1.y*w1r[4];
            sh_h1[i * 68 + lane] = fmaxf(a1, 0.0f);
            float4 c0 = ((const float4*)cav)[i * 2];
            float4 c1 = ((const float4*)cav)[i * 2 + 1];
            float a2 = b1r + c0.y*w1r[0] + c0.z*w1r[1] + c0.w*w1r[2] + c1.x*w1r[3] + c1.y*w1r[4];
            sh_h2[i * 68 + lane] = fmaxf(a2, 0.0f);
        }
    }
    __syncthreads();

    // ================= B2: GEMMs (waves 0-3) + degrees + avec =================
    if (wave < 4) {
        const int gw = wave & 1;
        const float* H = (wave < 2) ? sh_h1 : sh_h2;
        float* F  = (wave < 2) ? sh_f1 : sh_f2;
        float* NN = (wave < 2) ? sh_n1 : sh_n2;
        const int rr = lane >> 2, oq = lane & 3;
        const int i0 = 32 * gw + rr, i1 = i0 + 16;
        float4 a00 = make_float4(0,0,0,0), a01 = a00, a10 = a00, a11 = a00;
        #pragma unroll 4
        for (int k = 0; k < 64; ++k) {
            float  ha = H[i0 * 68 + k];
            float  hb = H[i1 * 68 + k];
            float4 wa = *(const float4*)(sh_w2 + k * 32 + 4 * oq);
            float4 wb = *(const float4*)(sh_w2 + k * 32 + 16 + 4 * oq);
            fma4(a00, ha, wa); fma4(a01, ha, wb);
            fma4(a10, hb, wa); fma4(a11, hb, wb);
        }
        float4 b2a = *(const float4*)(sh_nb2 + 4 * oq);
        float4 b2b = *(const float4*)(sh_nb2 + 16 + 4 * oq);
        add4(a00, b2a); add4(a01, b2b); add4(a10, b2a); add4(a11, b2b);
        *(float4*)(F + i0 * 36 + 4 * oq)      = a00;
        *(float4*)(F + i0 * 36 + 16 + 4 * oq) = a01;
        *(float4*)(F + i1 * 36 + 4 * oq)      = a10;
        *(float4*)(F + i1 * 36 + 16 + 4 * oq) = a11;
        float sq0 = quad_sum(dot4(a00, a00) + dot4(a01, a01));
        float sq1 = quad_sum(dot4(a10, a10) + dot4(a11, a11));
        if (oq == 0) {
            NN[i0] = fmaxf(sqrtf(sq0), 1e-8f);
            NN[i1] = fmaxf(sqrtf(sq1), 1e-8f);
        }
    } else if (wave == 4) {            // Dr + Tdeg
        float c1v = sh_cls1[lane], d = 0.0f;
        for (int j = 0; j < 64; ++j) d += (c1v == sh_cls2[j]) ? 1.0f : 0.0f;
        sh_Dr[lane] = d;
        float t = d;
        #pragma unroll
        for (int off = 32; off > 0; off >>= 1) t += __shfl_xor(t, off);
        if (lane == 0) sh_sc[2] = t;
    } else if (wave == 5) {            // Dc
        float c2v = sh_cls2[lane], d = 0.0f;
        for (int i = 0; i < 64; ++i) d += (sh_cls1[i] == c2v) ? 1.0f : 0.0f;
        sh_Dc[lane] = d;
    } else if (wave == 6 && lane < 16) {   // avec
        int o = lane;
        float ax = 0, av = 0, as_ = 0, aw = 0, au = 0, ae = 0, a1 = 0;
        for (int k = 0; k < 16; ++k) {
            float s0k = sw0[k], c0k = cw0[k], b0k = sb0[k] + cb0[k];
            float s1ko = sw1[k * 16 + o], c1ko = cw1[k * 16 + o];
            ax += s0k * s1ko;  av += c0k * s1ko + s0k * c1ko;  as_ += s1ko;
            aw += c0k * c1ko;  au += c1ko;  ae += b0k * c1ko;  a1 += b0k * s1ko;
        }
        a1 += sb1[o] + cb1[o];
        sh_avec[0*16+o] = ax; sh_avec[1*16+o] = av; sh_avec[2*16+o] = as_;
        sh_avec[3*16+o] = aw; sh_avec[4*16+o] = au; sh_avec[5*16+o] = ae;
        sh_avec[6*16+o] = a1;
    }
    __syncthreads();

    // ================= B3: cosine dots (waves 0-3) + coef + per-thread consts ==
    if (wave < 4) {
        const int sc = lane & 15, rc = lane >> 4;
        float dt[4][4];
        #pragma unroll
        for (int m = 0; m < 4; ++m)
            #pragma unroll
            for (int k = 0; k < 4; ++k) dt[m][k] = 0.0f;
        for (int kq = 0; kq < 8; ++kq) {
            float4 f2q[4];
            #pragma unroll
            for (int k = 0; k < 4; ++k)
                f2q[k] = *(const float4*)(sh_f2 + (sc + 16 * k) * 36 + 4 * kq);
            #pragma unroll
            for (int m = 0; m < 4; ++m) {
                int rrow = 16 * m + 4 * wave + rc;
                float4 f1q = *(const float4*)(sh_f1 + rrow * 36 + 4 * kq);
                #pragma unroll
                for (int k = 0; k < 4; ++k) dt[m][k] += dot4(f1q, f2q[k]);
            }
        }
        #pragma unroll
        for (int m = 0; m < 4; ++m) {
            int rrow = 16 * m + 4 * wave + rc;
            *(float4*)(sh_h1 + rrow * 68 + 4 * sc) =
                make_float4(dt[m][0], dt[m][1], dt[m][2], dt[m][3]);
        }
    } else if (wave == 4 && lane < 18) {
        int t = lane; float c = 0.0f;
        if (t == 0)      { for (int k = 0; k < 16; ++k) c += sw0[k] * kw0[k]; }
        else if (t == 1) { for (int k = 0; k < 16; ++k) c += cw0[k] * kw0[k]; }
        else if (t == 2) { for (int k = 0; k < 16; ++k) c += (sb0[k] + cb0[k]) * kw0[k]; c += kb0[0]; }
        else if (t < 10) { int v = t - 3;
            for (int o = 0; o < 16; ++o) c += sh_avec[v * 16 + o] * kw1[o];
            if (v == 6) c += kb1[0];
        } else if (t < 17) { int v = t - 10;
            for (int o = 0; o < 16; ++o) c += sh_avec[v * 16 + o] * fcw[o];
            if (v == 6) c += fcb[0];
        } else { for (int o = 0; o < 16; ++o) c += fcw[o]; }
        sh_coef[t] = c;
    } else if (wave == 5) {
        sh_Cp[lane] = 0.0f;
    }
    // per-thread constants (j = s+16k)
    const float cls1r = sh_cls1[r];
    const float Tdeg = sh_sc[2], Drr = sh_Dr[r];
    const float n1r = sh_n1[r], cf1r = sh_cf1[r];
    float mmq[4], dqv[4], cfq[4], n2q[4];
    #pragma unroll
    for (int k = 0; k < 4; ++k) {
        int j = s + 16 * k;
        float mm = (cls1r == sh_cls2[j]) ? 1.0f : 0.0f;
        mmq[k] = mm;
        dqv[k] = (mm != 0.0f) ? (1.0f / sqrtf(Tdeg - Drr - sh_Dc[j] + 3.0f)) : 1.0f;
        cfq[k] = sqrtf(cf1r * sh_cf2[j]);
        n2q[k] = sh_n2[j];
    }
    __syncthreads();

    // ================= B3.5: x0 from dots =================
    float x0[4];
    {
        float4 dq4 = *(const float4*)(sh_h1 + r * 68 + 4 * s);
        const float da[4] = {dq4.x, dq4.y, dq4.z, dq4.w};
        #pragma unroll
        for (int k = 0; k < 4; ++k)
            x0[k] = mmq[k] * cfq[k] * (da[k] / (n1r * n2q[k]));
    }
    __syncthreads();

    // ================= matvec A: v0 = normA x0, oe = normA 1 =================
    float v0[4], oe[4];
    {
        float ones[4] = {1.0f, 1.0f, 1.0f, 1.0f};
        matvec_dual(x0, ones, mmq, dqv, v0, oe, tid,
                    sh_WR1, sh_WR2, sh_WC1p, sh_WC2p, sh_h1, sh_sc);
    }

    // ================= t0 -> sinkhorn0 -> s0 =================
    const int pr = 4 * (r & 15) + (r >> 4);   // sigma^-1(r)
    float t0q[4], t0t[4];
    {
        float c0 = sh_coef[0], c1 = sh_coef[1], c2 = sh_coef[2];
        #pragma unroll
        for (int k = 0; k < 4; ++k) t0q[k] = (c0 * x0[k] + c1 * v0[k] + c2) * TAU_INV;
    }
    *(float4*)(sh_h2 + r * 68 + 4 * s) = make_float4(t0q[0], t0q[1], t0q[2], t0q[3]);
    __syncthreads();
    #pragma unroll
    for (int k = 0; k < 4; ++k) t0t[k] = sh_h2[(s + 16 * k) * 68 + pr];
    sinkhorn_rc(t0q, t0t, tid, sh_Rp, sh_Cp);
    float s0[4];
    {
        float Rr = sh_Rp[pr];
        float4 cc = *(const float4*)(sh_Cp + 4 * s);
        const float ca[4] = {cc.x, cc.y, cc.z, cc.w};
        #pragma unroll
        for (int k = 0; k < 4; ++k) s0[k] = __expf(t0q[k] - Rr - ca[k]);
    }

    // ================= matvec B + tacc/sacc =================
    float ov[4], os[4];
    matvec_dual(v0, s0, mmq, dqv, ov, os, tid,
                sh_WR1, sh_WR2, sh_WC1p, sh_WC2p, sh_h1, sh_sc);
    float tacc[4], sacc[4];
    {
        float ctx = sh_coef[3], ctv = sh_coef[4], cts = sh_coef[5];
        float cw_ = sh_coef[6], cu_ = sh_coef[7], ce_ = sh_coef[8], ct1 = sh_coef[9];
        float csx = sh_coef[10], csv = sh_coef[11], css = sh_coef[12];
        float cw2 = sh_coef[13], cu2 = sh_coef[14], ce2 = sh_coef[15], cs1 = sh_coef[16];
        #pragma unroll
        for (int k = 0; k < 4; ++k) {
            tacc[k] = ctx * x0[k] + ctv * v0[k] + cts * s0[k] + ct1
                    + cw_ * ov[k] + cu_ * os[k] + ce_ * oe[k];
            sacc[k] = csx * x0[k] + csv * v0[k] + css * s0[k] + cs1
                    + cw2 * ov[k] + cu2 * os[k] + ce2 * oe[k];
        }
    }

    // ================= t1 -> sinkhorn1 -> s1 =================
    float t1q[4], t1t[4];
    #pragma unroll
    for (int k = 0; k < 4; ++k) t1q[k] = tacc[k] * TAU_INV;
    if (tid < 64) sh_Cp[tid] = 0.0f;
    *(float4*)(sh_h2 + r * 68 + 4 * s) = make_float4(t1q[0], t1q[1], t1q[2], t1q[3]);
    __syncthreads();
    #pragma unroll
    for (int k = 0; k < 4; ++k) t1t[k] = sh_h2[(s + 16 * k) * 68 + pr];
    sinkhorn_rc(t1q, t1t, tid, sh_Rp, sh_Cp);
    {
        float c17 = sh_coef[17];
        float Rr = sh_Rp[pr];
        float4 cc = *(const float4*)(sh_Cp + 4 * s);
        const float ca[4] = {cc.x, cc.y, cc.z, cc.w};
        #pragma unroll
        for (int k = 0; k < 4; ++k) sacc[k] += c17 * __expf(t1q[k] - Rr - ca[k]);
    }
    __syncthreads();   // all Cp/sh_h2 reads done before overwrite

    // ================= transpose sacc -> sinkhorn2 -> output =================
    if (tid < 64) sh_Cp[tid] = 0.0f;
    *(float4*)(sh_h2 + r * 68 + 4 * s) = make_float4(sacc[0], sacc[1], sacc[2], sacc[3]);
    __syncthreads();
    float t2q[4], t2t[4];
    #pragma unroll
    for (int k = 0; k < 4; ++k) {
        t2q[k] = sh_h2[(s + 16 * k) * 68 + pr] * TAU_INV;  // t2[r][j] = sacc[j*64+r]
        t2t[k] = sacc[k] * TAU_INV;                         // own quad = t2 column r
    }
    sinkhorn_rc(t2q, t2t, tid, sh_Rp, sh_Cp);
    {
        float Rr = sh_Rp[pr];
        float4 cc = *(const float4*)(sh_Cp + 4 * s);
        const float ca[4] = {cc.x, cc.y, cc.z, cc.w};
        #pragma unroll
        for (int k = 0; k < 4; ++k)
            out[r * 64 + s + 16 * k] = __expf(t2q[k] - Rr - ca[k]);
    }
}

extern "C" void kernel_launch(void* const* d_in, const int* in_sizes, int n_in,
                              void* d_out, int out_size, void* d_ws, size_t ws_size,
                              hipStream_t stream) {
    const float* ego = (const float*)d_in[0];
    const float* cav = (const float*)d_in[1];
    const float* nw1 = (const float*)d_in[2];
    const float* nb1 = (const float*)d_in[3];
    const float* nw2 = (const float*)d_in[4];
    const float* nb2 = (const float*)d_in[5];
    // d_in[6..9] = edge MLP weights: dead code (edge values only feed the (K!=0) pattern)
    const float* sw0 = (const float*)d_in[10];
    const float* sb0 = (const float*)d_in[11];
    const float* cw0 = (const float*)d_in[12];
    const float* cb0 = (const float*)d_in[13];
    const float* kw0 = (const float*)d_in[14];
    const float* kb0 = (const float*)d_in[15];
    const float* sw1 = (const float*)d_in[16];
    const float* sb1 = (const float*)d_in[17];
    const float* cw1 = (const float*)d_in[18];
    const float* cb1 = (const float*)d_in[19];
    const float* kw1 = (const float*)d_in[20];
    const float* kb1 = (const float*)d_in[21];
    const float* fcw = (const float*)d_in[22];
    const float* fcb = (const float*)d_in[23];

    gcn_match_kernel<<<dim3(1), dim3(1024), 0, stream>>>(
        ego, cav, nw1, nb1, nw2, nb2,
        sw0, sb0, cw0, cb0, kw0, kb0,
        sw1, sb1, cw1, cb1, kw1, kb1,
        fcw, fcb, (float*)d_out);
}

// Round 5
// 123.951 us; speedup vs baseline: 2.2448x; 1.1009x over previous
//
#include <hip/hip_runtime.h>
#include <math.h>

// GCN graph-matching net. Verified reductions (R0-R3, absmax ~0):
//  - K off-diag values only used via (K != 0) -> class-match pattern; edge MLPs dead.
//  - normA @ u collapses to O(N) inclusion-exclusion; x stays rank<=7.
//  - Sinkhorn in R/C-scaling form: log_s = t - R_i - C_j; t register-resident both orientations.
// R4: latency-lean sinkhorn:
//  - base-2 domain (native v_exp_f32/v_log_f32), t pre-scaled by (1/tau)*log2(e).
//  - incremental shifts: after any normalization log_s <= 0, so shift by own-line previous
//    R/C (registers) instead of a max reduction -> no max tree in steps 1..19.
//  - step 0 computed on registers BEFORE the transpose barrier (merges 2 barriers).
//  - avec/coef computed by spare waves in P0/P1 (cold global loads overlap MLP/GEMM).
//  - cls2/cf2/n2/Dc stored permuted -> per-thread consts are 4x b128 LDS reads.

#define SK_SCALE 28.853900817779268f   // (1/TAU = 20) * log2(e)

template<int CTRL>
__device__ __forceinline__ float dppf(float x) {
    int xi = __float_as_int(x);
    int rr = __builtin_amdgcn_update_dpp(xi, xi, CTRL, 0xF, 0xF, false);
    return __int_as_float(rr);
}
__device__ __forceinline__ float red16_max(float v) {
    v = fmaxf(v, dppf<0xB1>(v));    // xor1 (quad_perm [1,0,3,2])
    v = fmaxf(v, dppf<0x4E>(v));    // xor2 (quad_perm [2,3,0,1])
    v = fmaxf(v, dppf<0x141>(v));   // row_half_mirror (xor7 within 8)
    v = fmaxf(v, dppf<0x140>(v));   // row_mirror (xor15 within 16)
    return v;
}
__device__ __forceinline__ float red16_sum(float v) {
    v += dppf<0xB1>(v); v += dppf<0x4E>(v); v += dppf<0x141>(v); v += dppf<0x140>(v);
    return v;
}
__device__ __forceinline__ float quad_sum(float v) {
    v += dppf<0xB1>(v); v += dppf<0x4E>(v);
    return v;
}
__device__ __forceinline__ float e2f(float x) { return __builtin_amdgcn_exp2f(x); }
__device__ __forceinline__ float l2f(float x) { return __builtin_amdgcn_logf(x); }  // log2
__device__ __forceinline__ float dot4(const float4 a, const float4 b) {
    return a.x*b.x + a.y*b.y + a.z*b.z + a.w*b.w;
}
__device__ __forceinline__ void fma4(float4& a, float b, const float4 c) {
    a.x += b*c.x; a.y += b*c.y; a.z += b*c.z; a.w += b*c.w;
}
__device__ __forceinline__ void add4(float4& a, const float4 c) {
    a.x += c.x; a.y += c.y; a.z += c.z; a.w += c.w;
}

// Sinkhorn step 0 (row step, C=0) with max-subtraction; registers/DPP only.
__device__ __forceinline__ float sk_step0(const float* tq) {
    float m  = red16_max(fmaxf(fmaxf(tq[0], tq[1]), fmaxf(tq[2], tq[3])));
    float sm = red16_sum(e2f(tq[0]-m) + e2f(tq[1]-m) + e2f(tq[2]-m) + e2f(tq[3]-m));
    return m + l2f(sm);
}

// Iterations 1..19 (19 barriers). Caller did step 0, stored Rp[pr], barrier'd, loaded tt.
// Incremental shifts keep all exp2 args <= ~0 (post-normalization log-probs).
__device__ float sk_rest(const float* tq, const float* tt, float Rown,
                         int pr, int s, float* Rp, float* Cp) {
    float Cown;
    {   // it = 1 (col), C shift = 0
        float4 rq = *(const float4*)(Rp + 4 * s);
        float sm = red16_sum(e2f(tt[0]-rq.x) + e2f(tt[1]-rq.y) +
                             e2f(tt[2]-rq.z) + e2f(tt[3]-rq.w));
        Cown = l2f(fmaxf(sm, 1e-37f));
        if (s == 0) Cp[pr] = Cown;
        __syncthreads();
    }
    #pragma unroll 1
    for (int p = 0; p < 9; ++p) {
        {   // row step (its 2,4,...,18)
            float4 cq = *(const float4*)(Cp + 4 * s);
            float sm = red16_sum(e2f(tq[0]-cq.x-Rown) + e2f(tq[1]-cq.y-Rown) +
                                 e2f(tq[2]-cq.z-Rown) + e2f(tq[3]-cq.w-Rown));
            Rown += l2f(fmaxf(sm, 1e-37f));
            if (s == 0) Rp[pr] = Rown;
            __syncthreads();
        }
        {   // col step (its 3,5,...,19)
            float4 rq = *(const float4*)(Rp + 4 * s);
            float sm = red16_sum(e2f(tt[0]-rq.x-Cown) + e2f(tt[1]-rq.y-Cown) +
                                 e2f(tt[2]-rq.z-Cown) + e2f(tt[3]-rq.w-Cown));
            Cown += l2f(fmaxf(sm, 1e-37f));
            if (s == 0) Cp[pr] = Cown;
            __syncthreads();
        }
    }
    return Rown;
}

// Dual normA matvec on register quads (j = s+16k convention). WC stored permuted.
// 2 internal barriers, NO trailing barrier (callers use disjoint buffers).
__device__ void matvec_dual(const float* u1, const float* u2,
                            const float* mmq, const float* dq,
                            float* o1, float* o2, int tid,
                            float* WR1, float* WR2, float* WC1p, float* WC2p,
                            float* pwc, float* scW) {
    const int r = tid >> 4, s = tid & 15, lane = tid & 63, w = tid >> 6;
    float z1[4], z2[4];
    float rs1 = 0.0f, rs2 = 0.0f;
    #pragma unroll
    for (int k = 0; k < 4; ++k) {
        float md = mmq[k] * dq[k];
        z1[k] = md * u1[k];
        z2[k] = md * u2[k];
        rs1 += z1[k]; rs2 += z2[k];
    }
    rs1 = red16_sum(rs1); rs2 = red16_sum(rs2);
    if (s == 0) { WR1[r] = rs1; WR2[r] = rs2; }
    float p1[4], p2[4];
    #pragma unroll
    for (int k = 0; k < 4; ++k) {   // col partial over the wave's 4 rows
        float v = z1[k]; v += __shfl_xor(v, 16); v += __shfl_xor(v, 32); p1[k] = v;
        float u = z2[k]; u += __shfl_xor(u, 16); u += __shfl_xor(u, 32); p2[k] = u;
    }
    if (lane < 16) {
        ((float4*)pwc)[w * 16 + s]          = make_float4(p1[0], p1[1], p1[2], p1[3]);
        ((float4*)(pwc + 1024))[w * 16 + s] = make_float4(p2[0], p2[1], p2[2], p2[3]);
    }
    __syncthreads();
    if (tid < 64) {
        float c1 = 0.0f, c2 = 0.0f;
        #pragma unroll
        for (int ww = 0; ww < 16; ++ww) {
            c1 += pwc[ww * 64 + tid];
            c2 += pwc[1024 + ww * 64 + tid];
        }
        WC1p[tid] = c1; WC2p[tid] = c2;      // tid is the q-index -> permuted
    } else if (tid < 128) {
        float v = WR1[tid - 64];
        #pragma unroll
        for (int off = 32; off > 0; off >>= 1) v += __shfl_xor(v, off);
        if (tid == 64) scW[0] = v;
    } else if (tid < 192) {
        float v = WR2[tid - 128];
        #pragma unroll
        for (int off = 32; off > 0; off >>= 1) v += __shfl_xor(v, off);
        if (tid == 128) scW[1] = v;
    }
    __syncthreads();
    const float W1 = scW[0], W2 = scW[1];
    const float wr1 = WR1[r], wr2 = WR2[r];
    float4 wc1 = *(const float4*)(WC1p + 4 * s);
    float4 wc2 = *(const float4*)(WC2p + 4 * s);
    const float wc1a[4] = {wc1.x, wc1.y, wc1.z, wc1.w};
    const float wc2a[4] = {wc2.x, wc2.y, wc2.z, wc2.w};
    #pragma unroll
    for (int k = 0; k < 4; ++k) {
        float d = dq[k], mm = mmq[k];
        o1[k] = d * ((1.0f + mm) * d * u1[k] + mm * (W1 - wr1 - wc1a[k] + z1[k]));
        o2[k] = d * ((1.0f + mm) * d * u2[k] + mm * (W2 - wr2 - wc2a[k] + z2[k]));
    }
}

extern "C" __global__ __launch_bounds__(1024)
void gcn_match_kernel(const float* ego, const float* cav,
                      const float* nw1, const float* nb1, const float* nw2, const float* nb2,
                      const float* sw0, const float* sb0, const float* cw0, const float* cb0,
                      const float* kw0, const float* kb0,
                      const float* sw1, const float* sb1, const float* cw1, const float* cb1,
                      const float* kw1, const float* kb1,
                      const float* fcw, const float* fcb,
                      float* out) {
    __shared__ __align__(16) float sh_h1[64 * 68];   // ego hidden | dots | matvec pwc A/B
    __shared__ __align__(16) float sh_h2[64 * 68];   // cav hidden | sinkhorn transpose buf
    __shared__ __align__(16) float sh_f1[64 * 36];
    __shared__ __align__(16) float sh_f2[64 * 36];
    __shared__ __align__(16) float sh_w2[2048];
    __shared__ __align__(16) float sh_nb2[32];
    __shared__ float sh_cls1[64], sh_cf1[64];
    __shared__ __align__(16) float sh_cls2p[64], sh_cf2p[64];   // permuted
    __shared__ float sh_n1[64];
    __shared__ __align__(16) float sh_n2p[64];                  // permuted
    __shared__ float sh_Dr[64];
    __shared__ __align__(16) float sh_Dcp[64];                  // permuted
    __shared__ __align__(16) float sh_Rp[64], sh_Cp[64];        // permuted
    __shared__ float sh_WR1a[64], sh_WR2a[64], sh_WR1b[64], sh_WR2b[64];
    __shared__ __align__(16) float sh_WC1pa[64], sh_WC2pa[64], sh_WC1pb[64], sh_WC2pb[64];
    __shared__ float sh_avec[7 * 16];
    __shared__ float sh_coef[18];
    __shared__ float sh_sc[8];   // [0,1]=matvecA totals, [2]=Tdeg, [4,5]=matvecB totals

    const int tid  = threadIdx.x;
    const int wave = tid >> 6, lane = tid & 63;
    const int r = tid >> 4, s = tid & 15;
    const int pr = 4 * (r & 15) + (r >> 4);   // permutation sigma^-1(r)

    // ================= P0: staging + hidden MLP + avec =================
    if (tid < 512) ((float4*)sh_w2)[tid] = ((const float4*)nw2)[tid];
    if (tid < 32) sh_nb2[tid] = nb2[tid];
    if (tid < 64) { sh_cls1[tid] = ego[tid * 8 + 6]; sh_cf1[tid] = ego[tid * 8 + 7]; }
    else if (tid < 128) {
        int j = tid - 64, jp = 4 * (j & 15) + (j >> 4);
        sh_cls2p[jp] = cav[j * 8 + 6]; sh_cf2p[jp] = cav[j * 8 + 7];
    }
    if (wave < 8) {
        float w1r[5];
        #pragma unroll
        for (int f = 0; f < 5; ++f) w1r[f] = nw1[f * 64 + lane];
        float b1r = nb1[lane];
        #pragma unroll
        for (int p = 0; p < 8; ++p) {
            int i = (wave << 3) | p;
            float4 e0 = ((const float4*)ego)[i * 2];
            float4 e1 = ((const float4*)ego)[i * 2 + 1];
            sh_h1[i * 68 + lane] = fmaxf(
                b1r + e0.y*w1r[0] + e0.z*w1r[1] + e0.w*w1r[2] + e1.x*w1r[3] + e1.y*w1r[4], 0.0f);
            float4 c0 = ((const float4*)cav)[i * 2];
            float4 c1 = ((const float4*)cav)[i * 2 + 1];
            sh_h2[i * 68 + lane] = fmaxf(
                b1r + c0.y*w1r[0] + c0.z*w1r[1] + c0.w*w1r[2] + c1.x*w1r[3] + c1.y*w1r[4], 0.0f);
        }
    } else if (wave == 8 && lane < 16) {   // avec (cold loads overlap MLP)
        int o = lane;
        float ax = 0, av = 0, as_ = 0, aw = 0, au = 0, ae = 0, a1 = 0;
        for (int k = 0; k < 16; ++k) {
            float s0k = sw0[k], c0k = cw0[k], b0k = sb0[k] + cb0[k];
            float s1ko = sw1[k * 16 + o], c1ko = cw1[k * 16 + o];
            ax += s0k * s1ko;  av += c0k * s1ko + s0k * c1ko;  as_ += s1ko;
            aw += c0k * c1ko;  au += c1ko;  ae += b0k * c1ko;  a1 += b0k * s1ko;
        }
        a1 += sb1[o] + cb1[o];
        sh_avec[0*16+o] = ax; sh_avec[1*16+o] = av; sh_avec[2*16+o] = as_;
        sh_avec[3*16+o] = aw; sh_avec[4*16+o] = au; sh_avec[5*16+o] = ae;
        sh_avec[6*16+o] = a1;
    }
    __syncthreads();

    // ================= P1: GEMMs + degrees + coef =================
    if (wave < 4) {
        const int gw = wave & 1;
        const float* H = (wave < 2) ? sh_h1 : sh_h2;
        float* F = (wave < 2) ? sh_f1 : sh_f2;
        const int rr = lane >> 2, oq = lane & 3;
        const int i0 = 32 * gw + rr, i1 = i0 + 16;
        float4 a00 = make_float4(0,0,0,0), a01 = a00, a10 = a00, a11 = a00;
        #pragma unroll 4
        for (int k = 0; k < 64; ++k) {
            float  ha = H[i0 * 68 + k];
            float  hb = H[i1 * 68 + k];
            float4 wa = *(const float4*)(sh_w2 + k * 32 + 4 * oq);
            float4 wb = *(const float4*)(sh_w2 + k * 32 + 16 + 4 * oq);
            fma4(a00, ha, wa); fma4(a01, ha, wb);
            fma4(a10, hb, wa); fma4(a11, hb, wb);
        }
        float4 b2a = *(const float4*)(sh_nb2 + 4 * oq);
        float4 b2b = *(const float4*)(sh_nb2 + 16 + 4 * oq);
        add4(a00, b2a); add4(a01, b2b); add4(a10, b2a); add4(a11, b2b);
        *(float4*)(F + i0 * 36 + 4 * oq)      = a00;
        *(float4*)(F + i0 * 36 + 16 + 4 * oq) = a01;
        *(float4*)(F + i1 * 36 + 4 * oq)      = a10;
        *(float4*)(F + i1 * 36 + 16 + 4 * oq) = a11;
        float sq0 = quad_sum(dot4(a00, a00) + dot4(a01, a01));
        float sq1 = quad_sum(dot4(a10, a10) + dot4(a11, a11));
        if (oq == 0) {
            float v0n = fmaxf(sqrtf(sq0), 1e-8f);
            float v1n = fmaxf(sqrtf(sq1), 1e-8f);
            if (wave < 2) { sh_n1[i0] = v0n; sh_n1[i1] = v1n; }
            else {
                sh_n2p[4 * (i0 & 15) + (i0 >> 4)] = v0n;
                sh_n2p[4 * (i1 & 15) + (i1 >> 4)] = v1n;
            }
        }
    } else if (wave == 4) {            // Dr + Tdeg (cls2p order-independent)
        float c1v = sh_cls1[lane], d = 0.0f;
        for (int j = 0; j < 64; ++j) d += (c1v == sh_cls2p[j]) ? 1.0f : 0.0f;
        sh_Dr[lane] = d;
        float t = d;
        #pragma unroll
        for (int off = 32; off > 0; off >>= 1) t += __shfl_xor(t, off);
        if (lane == 0) sh_sc[2] = t;
    } else if (wave == 5) {            // Dc (permuted store)
        float c2v = sh_cls2p[4 * (lane & 15) + (lane >> 4)];
        float d = 0.0f;
        for (int i = 0; i < 64; ++i) d += (sh_cls1[i] == c2v) ? 1.0f : 0.0f;
        sh_Dcp[4 * (lane & 15) + (lane >> 4)] = d;
    } else if (wave == 6 && lane < 18) {   // coef (avec from P0)
        int t = lane; float c = 0.0f;
        if (t == 0)      { for (int k = 0; k < 16; ++k) c += sw0[k] * kw0[k]; }
        else if (t == 1) { for (int k = 0; k < 16; ++k) c += cw0[k] * kw0[k]; }
        else if (t == 2) { for (int k = 0; k < 16; ++k) c += (sb0[k] + cb0[k]) * kw0[k]; c += kb0[0]; }
        else if (t < 10) { int v = t - 3;
            for (int o = 0; o < 16; ++o) c += sh_avec[v * 16 + o] * kw1[o];
            if (v == 6) c += kb1[0];
        } else if (t < 17) { int v = t - 10;
            for (int o = 0; o < 16; ++o) c += sh_avec[v * 16 + o] * fcw[o];
            if (v == 6) c += fcb[0];
        } else { for (int o = 0; o < 16; ++o) c += fcw[o]; }
        sh_coef[t] = c;
    }
    __syncthreads();

    // ================= P2: cosine dots + per-thread consts =================
    if (wave < 4) {
        const int sc = lane & 15, rc = lane >> 4;
        float dt[4][4];
        #pragma unroll
        for (int m = 0; m < 4; ++m)
            #pragma unroll
            for (int k = 0; k < 4; ++k) dt[m][k] = 0.0f;
        for (int kq = 0; kq < 8; ++kq) {
            float4 f2q[4];
            #pragma unroll
            for (int k = 0; k < 4; ++k)
                f2q[k] = *(const float4*)(sh_f2 + (sc + 16 * k) * 36 + 4 * kq);
            #pragma unroll
            for (int m = 0; m < 4; ++m) {
                int rrow = 16 * m + 4 * wave + rc;
                float4 f1q = *(const float4*)(sh_f1 + rrow * 36 + 4 * kq);
                #pragma unroll
                for (int k = 0; k < 4; ++k) dt[m][k] += dot4(f1q, f2q[k]);
            }
        }
        #pragma unroll
        for (int m = 0; m < 4; ++m) {
            int rrow = 16 * m + 4 * wave + rc;
            *(float4*)(sh_h1 + rrow * 68 + 4 * sc) =
                make_float4(dt[m][0], dt[m][1], dt[m][2], dt[m][3]);
        }
    }
    // per-thread constants (j = s+16k), permuted b128 loads
    float mmq[4], dqv[4], cfq[4], n2q[4];
    {
        const float cls1r = sh_cls1[r];
        const float Tdeg = sh_sc[2], Drr = sh_Dr[r];
        const float cf1r = sh_cf1[r];
        float4 c2 = *(const float4*)(sh_cls2p + 4 * s);
        float4 cf = *(const float4*)(sh_cf2p + 4 * s);
        float4 n2 = *(const float4*)(sh_n2p + 4 * s);
        float4 dc = *(const float4*)(sh_Dcp + 4 * s);
        const float c2a[4] = {c2.x, c2.y, c2.z, c2.w};
        const float cfa[4] = {cf.x, cf.y, cf.z, cf.w};
        const float n2a[4] = {n2.x, n2.y, n2.z, n2.w};
        const float dca[4] = {dc.x, dc.y, dc.z, dc.w};
        #pragma unroll
        for (int k = 0; k < 4; ++k) {
            float mm = (cls1r == c2a[k]) ? 1.0f : 0.0f;
            mmq[k] = mm;
            dqv[k] = (mm != 0.0f) ? (1.0f / sqrtf(Tdeg - Drr - dca[k] + 3.0f)) : 1.0f;
            cfq[k] = sqrtf(cf1r * cfa[k]);
            n2q[k] = n2a[k];
        }
    }
    __syncthreads();

    // ================= P3: x0 from dots =================
    float x0[4];
    {
        const float n1r = sh_n1[r];
        float4 dq4 = *(const float4*)(sh_h1 + r * 68 + 4 * s);
        const float da[4] = {dq4.x, dq4.y, dq4.z, dq4.w};
        #pragma unroll
        for (int k = 0; k < 4; ++k)
            x0[k] = mmq[k] * cfq[k] * (da[k] / (n1r * n2q[k]));
    }
    __syncthreads();   // protect dots before matvecA overwrites sh_h1

    // ================= matvec A: v0 = normA x0, oe = normA 1 =================
    float v0[4], oe[4];
    {
        float ones[4] = {1.0f, 1.0f, 1.0f, 1.0f};
        matvec_dual(x0, ones, mmq, dqv, v0, oe, tid,
                    sh_WR1a, sh_WR2a, sh_WC1pa, sh_WC2pa, sh_h1, sh_sc);
    }

    // ================= t0 -> sinkhorn0 -> s0 =================
    float t0q[4];
    {
        float c0 = sh_coef[0], c1 = sh_coef[1], c2c = sh_coef[2];
        #pragma unroll
        for (int k = 0; k < 4; ++k) t0q[k] = (c0 * x0[k] + c1 * v0[k] + c2c) * SK_SCALE;
    }
    *(float4*)(sh_h2 + r * 68 + 4 * s) = make_float4(t0q[0], t0q[1], t0q[2], t0q[3]);
    float R0 = sk_step0(t0q);          // overlaps the store
    if (s == 0) sh_Rp[pr] = R0;
    __syncthreads();
    float t0t[4];
    #pragma unroll
    for (int k = 0; k < 4; ++k) t0t[k] = sh_h2[(s + 16 * k) * 68 + pr];
    R0 = sk_rest(t0q, t0t, R0, pr, s, sh_Rp, sh_Cp);
    float s0[4];
    {
        float4 cc = *(const float4*)(sh_Cp + 4 * s);
        const float ca[4] = {cc.x, cc.y, cc.z, cc.w};
        #pragma unroll
        for (int k = 0; k < 4; ++k) s0[k] = e2f(t0q[k] - R0 - ca[k]);
    }

    // ================= matvec B + tacc/sacc =================
    float ov[4], os[4];
    matvec_dual(v0, s0, mmq, dqv, ov, os, tid,
                sh_WR1b, sh_WR2b, sh_WC1pb, sh_WC2pb, sh_h1 + 2048, sh_sc + 4);
    float tacc[4], sacc[4];
    {
        float ctx = sh_coef[3], ctv = sh_coef[4], cts = sh_coef[5];
        float cw_ = sh_coef[6], cu_ = sh_coef[7], ce_ = sh_coef[8], ct1 = sh_coef[9];
        float csx = sh_coef[10], csv = sh_coef[11], css = sh_coef[12];
        float cw2 = sh_coef[13], cu2 = sh_coef[14], ce2 = sh_coef[15], cs1 = sh_coef[16];
        #pragma unroll
        for (int k = 0; k < 4; ++k) {
            tacc[k] = ctx * x0[k] + ctv * v0[k] + cts * s0[k] + ct1
                    + cw_ * ov[k] + cu_ * os[k] + ce_ * oe[k];
            sacc[k] = csx * x0[k] + csv * v0[k] + css * s0[k] + cs1
                    + cw2 * ov[k] + cu2 * os[k] + ce2 * oe[k];
        }
    }

    // ================= t1 -> sinkhorn1 -> sacc += c17*s1 =================
    float t1q[4];
    #pragma unroll
    for (int k = 0; k < 4; ++k) t1q[k] = tacc[k] * SK_SCALE;
    *(float4*)(sh_h2 + r * 68 + 4 * s) = make_float4(t1q[0], t1q[1], t1q[2], t1q[3]);
    float R1 = sk_step0(t1q);
    if (s == 0) sh_Rp[pr] = R1;
    __syncthreads();
    float t1t[4];
    #pragma unroll
    for (int k = 0; k < 4; ++k) t1t[k] = sh_h2[(s + 16 * k) * 68 + pr];
    R1 = sk_rest(t1q, t1t, R1, pr, s, sh_Rp, sh_Cp);
    {
        float c17 = sh_coef[17];
        float4 cc = *(const float4*)(sh_Cp + 4 * s);
        const float ca[4] = {cc.x, cc.y, cc.z, cc.w};
        #pragma unroll
        for (int k = 0; k < 4; ++k) sacc[k] += c17 * e2f(t1q[k] - R1 - ca[k]);
    }

    // ================= transpose sacc -> sinkhorn2 -> output =================
    *(float4*)(sh_h2 + r * 68 + 4 * s) = make_float4(sacc[0], sacc[1], sacc[2], sacc[3]);
    __syncthreads();
    float t2q[4], t2t[4];
    #pragma unroll
    for (int k = 0; k < 4; ++k) {
        t2q[k] = sh_h2[(s + 16 * k) * 68 + pr] * SK_SCALE;  // row r of s (= sacc^T)
        t2t[k] = sacc[k] * SK_SCALE;                         // own quad = s column r
    }
    float R2 = sk_step0(t2q);
    if (s == 0) sh_Rp[pr] = R2;
    __syncthreads();
    R2 = sk_rest(t2q, t2t, R2, pr, s, sh_Rp, sh_Cp);
    {
        float4 cc = *(const float4*)(sh_Cp + 4 * s);
        const float ca[4] = {cc.x, cc.y, cc.z, cc.w};
        #pragma unroll
        for (int k = 0; k < 4; ++k)
            out[(r << 6) + s + (k << 4)] = e2f(t2q[k] - R2 - ca[k]);
    }
}

extern "C" void kernel_launch(void* const* d_in, const int* in_sizes, int n_in,
                              void* d_out, int out_size, void* d_ws, size_t ws_size,
                              hipStream_t stream) {
    const float* ego = (const float*)d_in[0];
    const float* cav = (const float*)d_in[1];
    const float* nw1 = (const float*)d_in[2];
    const float* nb1 = (const float*)d_in[3];
    const float* nw2 = (const float*)d_in[4];
    const float* nb2 = (const float*)d_in[5];
    // d_in[6..9] = edge MLP weights: dead code (edge values only feed the (K!=0) pattern)
    const float* sw0 = (const float*)d_in[10];
    const float* sb0 = (const float*)d_in[11];
    const float* cw0 = (const float*)d_in[12];
    const float* cb0 = (const float*)d_in[13];
    const float* kw0 = (const float*)d_in[14];
    const float* kb0 = (const float*)d_in[15];
    const float* sw1 = (const float*)d_in[16];
    const float* sb1 = (const float*)d_in[17];
    const float* cw1 = (const float*)d_in[18];
    const float* cb1 = (const float*)d_in[19];
    const float* kw1 = (const float*)d_in[20];
    const float* kb1 = (const float*)d_in[21];
    const float* fcw = (const float*)d_in[22];
    const float* fcb = (const float*)d_in[23];

    gcn_match_kernel<<<dim3(1), dim3(1024), 0, stream>>>(
        ego, cav, nw1, nb1, nw2, nb2,
        sw0, sb0, cw0, cb0, kw0, kb0,
        sw1, sb1, cw1, cb1, kw1, kb1,
        fcw, fcb, (float*)d_out);
}

// Round 6
// 123.901 us; speedup vs baseline: 2.2457x; 1.0004x over previous
//
#include <hip/hip_runtime.h>
#include <math.h>

// GCN graph-matching net. Verified reductions (R0-R4, absmax ~0):
//  - K off-diag values only used via (K != 0) -> class-match pattern; edge MLPs dead.
//  - normA @ u collapses to O(N) inclusion-exclusion; x stays rank<=7.
// R5: op-count attack on the single-CU LDS pipe + VALU issue:
//  - MULTIPLICATIVE sinkhorn: A = 2^(t - rowmax) built once; steps are u=1/(Av), v=1/(A^T u)
//    (b128 read + 4 fma + red16 + rcp + write). No exp/log in the 59-step loop.
//  - Dual-orientation registers everywhere: every vector kept in (row r, cols s+16k) AND
//    (rows s+16k, col r) layouts -> matvecs are 1 barrier (col sums = transposed row sums,
//    W = red16 of WC-quad), and ZERO LDS transposes in the whole kernel.
//  - MLP writes h TRANSPOSED (stride 68, lane=node: conflict-free) -> GEMM reads h as b128;
//    2 waves do both GEMMs (w2 read redundancy 4x -> 2x).
//  - Degrees via red16 of mm registers (no 64-iter scalar loops).

#define SK_SCALE 28.853900817779268f   // (1/TAU = 20) * log2(e)

template<int CTRL>
__device__ __forceinline__ float dppf(float x) {
    int xi = __float_as_int(x);
    int rr = __builtin_amdgcn_update_dpp(xi, xi, CTRL, 0xF, 0xF, false);
    return __int_as_float(rr);
}
__device__ __forceinline__ float red16_max(float v) {
    v = fmaxf(v, dppf<0xB1>(v));    // xor1 (quad_perm [1,0,3,2])
    v = fmaxf(v, dppf<0x4E>(v));    // xor2 (quad_perm [2,3,0,1])
    v = fmaxf(v, dppf<0x141>(v));   // row_half_mirror
    v = fmaxf(v, dppf<0x140>(v));   // row_mirror
    return v;
}
__device__ __forceinline__ float red16_sum(float v) {
    v += dppf<0xB1>(v); v += dppf<0x4E>(v); v += dppf<0x141>(v); v += dppf<0x140>(v);
    return v;
}
__device__ __forceinline__ float e2f(float x) { return __builtin_amdgcn_exp2f(x); }
__device__ __forceinline__ float rcpf(float x) { return __builtin_amdgcn_rcpf(x); }
__device__ __forceinline__ float dot4(const float4 a, const float4 b) {
    return a.x*b.x + a.y*b.y + a.z*b.z + a.w*b.w;
}
__device__ __forceinline__ void fma4(float4& a, float b, const float4 c) {
    a.x += b*c.x; a.y += b*c.y; a.z += b*c.z; a.w += b*c.w;
}
__device__ __forceinline__ void add4(float4& a, const float4 c) {
    a.x += c.x; a.y += c.y; a.z += c.z; a.w += c.w;
}
__device__ __forceinline__ void ld4(const float* p, float* o) {
    float4 v = *(const float4*)p; o[0]=v.x; o[1]=v.y; o[2]=v.z; o[3]=v.w;
}

// Multiplicative sinkhorn, 20 steps (it0 row ... it19 col), 20 barriers.
// tq: t (log2-domain, pre-scaled) row r cols s+16k; tt: rows s+16k col r.
// Leaves A-factors in aq/att, final row scale in *u_out (it18), col scale *v_out (it19).
__device__ void sk_mult(const float* tq, const float* tt, int s, int pr,
                        float* up, float* vp, float* rmp,
                        float* aq, float* att, float* u_out, float* v_out) {
    float rm = red16_max(fmaxf(fmaxf(tq[0], tq[1]), fmaxf(tq[2], tq[3])));
    #pragma unroll
    for (int k = 0; k < 4; ++k) aq[k] = e2f(tq[k] - rm);
    float u = rcpf(red16_sum(aq[0] + aq[1] + aq[2] + aq[3]));   // it0 (v=1)
    if (s == 0) { rmp[pr] = rm; up[pr] = u; }
    __syncthreads();
    float rmq[4]; ld4(rmp + 4*s, rmq);
    #pragma unroll
    for (int k = 0; k < 4; ++k) att[k] = e2f(tt[k] - rmq[k]);
    float v;
    {   // it1 (col)
        float uq[4]; ld4(up + 4*s, uq);
        v = rcpf(red16_sum(att[0]*uq[0] + att[1]*uq[1] + att[2]*uq[2] + att[3]*uq[3]));
        if (s == 0) vp[pr] = v;
        __syncthreads();
    }
    #pragma unroll 1
    for (int p = 0; p < 9; ++p) {   // its 2..19
        float vq[4]; ld4(vp + 4*s, vq);
        u = rcpf(red16_sum(aq[0]*vq[0] + aq[1]*vq[1] + aq[2]*vq[2] + aq[3]*vq[3]));
        if (s == 0) up[pr] = u;
        __syncthreads();
        float uq[4]; ld4(up + 4*s, uq);
        v = rcpf(red16_sum(att[0]*uq[0] + att[1]*uq[1] + att[2]*uq[2] + att[3]*uq[3]));
        if (s == 0) vp[pr] = v;
        __syncthreads();
    }
    *u_out = u; *v_out = v;
}

// normA matvec, dual vectors (u1,u2) x dual orientations, ONE barrier.
__device__ void matvec_dual(const float* u1, const float* u1t, const float* u2, const float* u2t,
                            const float* mmq, const float* dqv, const float* mmt, const float* dqt,
                            float* o1, float* o1t, float* o2, float* o2t,
                            int s, int pr,
                            float* WR1p, float* WC1p, float* WR2p, float* WC2p) {
    float z1[4], z2[4], z1t[4], z2t[4];
    float rs1 = 0, rs2 = 0, cs1 = 0, cs2 = 0;
    #pragma unroll
    for (int k = 0; k < 4; ++k) {
        float md = mmq[k] * dqv[k], mdt = mmt[k] * dqt[k];
        z1[k] = md * u1[k];   z2[k] = md * u2[k];
        z1t[k] = mdt * u1t[k]; z2t[k] = mdt * u2t[k];
        rs1 += z1[k]; rs2 += z2[k]; cs1 += z1t[k]; cs2 += z2t[k];
    }
    rs1 = red16_sum(rs1); rs2 = red16_sum(rs2);
    cs1 = red16_sum(cs1); cs2 = red16_sum(cs2);
    if (s == 0) { WR1p[pr] = rs1; WR2p[pr] = rs2; WC1p[pr] = cs1; WC2p[pr] = cs2; }
    __syncthreads();
    float wr1[4], wc1[4], wr2[4], wc2[4];
    ld4(WR1p + 4*s, wr1); ld4(WC1p + 4*s, wc1);
    ld4(WR2p + 4*s, wr2); ld4(WC2p + 4*s, wc2);
    float W1 = red16_sum(wc1[0] + wc1[1] + wc1[2] + wc1[3]);
    float W2 = red16_sum(wc2[0] + wc2[1] + wc2[2] + wc2[3]);
    #pragma unroll
    for (int k = 0; k < 4; ++k) {
        float d = dqv[k], mm = mmq[k], dt = dqt[k], mt = mmt[k];
        o1[k]  = d  * ((1.0f + mm) * d  * u1[k]  + mm * (W1 - rs1 - wc1[k] + z1[k]));
        o2[k]  = d  * ((1.0f + mm) * d  * u2[k]  + mm * (W2 - rs2 - wc2[k] + z2[k]));
        o1t[k] = dt * ((1.0f + mt) * dt * u1t[k] + mt * (W1 - wr1[k] - cs1 + z1t[k]));
        o2t[k] = dt * ((1.0f + mt) * dt * u2t[k] + mt * (W2 - wr2[k] - cs2 + z2t[k]));
    }
}

extern "C" __global__ __launch_bounds__(1024)
void gcn_match_kernel(const float* ego, const float* cav,
                      const float* nw1, const float* nb1, const float* nw2, const float* nb2,
                      const float* sw0, const float* sb0, const float* cw0, const float* cb0,
                      const float* kw0, const float* kb0,
                      const float* sw1, const float* sb1, const float* cw1, const float* cb1,
                      const float* kw1, const float* kb1,
                      const float* fcw, const float* fcb,
                      float* out) {
    __shared__ __align__(16) float sh_hT1[64 * 68];   // ego hidden^T | later: dots matrix
    __shared__ __align__(16) float sh_hT2[64 * 68];   // cav hidden^T
    __shared__ __align__(16) float sh_w2[2048];
    __shared__ __align__(16) float sh_f1[64 * 36];
    __shared__ __align__(16) float sh_f2[64 * 36];
    __shared__ __align__(16) float sh_nb2[32];
    __shared__ float sh_cls1[64], sh_cf1[64], sh_n1[64];
    __shared__ __align__(16) float sh_cls1p[64], sh_cf1p[64], sh_n1p[64];
    __shared__ __align__(16) float sh_cls2p[64], sh_cf2p[64], sh_n2p[64];
    __shared__ __align__(16) float sh_Drp[64], sh_Dcp[64];
    __shared__ __align__(16) float sh_rmp[64], sh_up[64], sh_vp[64];
    __shared__ __align__(16) float sh_WR1p[64], sh_WC1p[64], sh_WR2p[64], sh_WC2p[64];
    __shared__ float sh_avec[7 * 16];
    __shared__ float sh_coef[18];

    const int tid  = threadIdx.x;
    const int wave = tid >> 6, lane = tid & 63;
    const int r = tid >> 4, s = tid & 15;
    const int pr = 4 * (r & 15) + (r >> 4);   // sigma^-1(r)
    float* sh_dots = sh_hT1;                  // alias after GEMM

    // ================= P0: staging + hidden MLP (transposed store) =================
    if (tid < 512) ((float4*)sh_w2)[tid] = ((const float4*)nw2)[tid];
    if (tid < 32) sh_nb2[tid] = nb2[tid];
    if (tid < 64) {
        float c = ego[tid * 8 + 6], f = ego[tid * 8 + 7];
        int p = 4 * (tid & 15) + (tid >> 4);
        sh_cls1[tid] = c; sh_cf1[tid] = f; sh_cls1p[p] = c; sh_cf1p[p] = f;
    } else if (tid < 128) {
        int j = tid - 64, p = 4 * (j & 15) + (j >> 4);
        sh_cls2p[p] = cav[j * 8 + 6]; sh_cf2p[p] = cav[j * 8 + 7];
    }
    {   // lane = node i; wave covers 8 k's; w1/b1 wave-uniform scalar loads
        const float* X = (wave < 8) ? ego : cav;
        float* HT = (wave < 8) ? sh_hT1 : sh_hT2;
        const int k0 = (wave & 7) * 8;
        float4 xa = ((const float4*)X)[lane * 2];
        float4 xb = ((const float4*)X)[lane * 2 + 1];
        #pragma unroll
        for (int kk = 0; kk < 8; ++kk) {
            int k = k0 + kk;
            float acc = nb1[k] + xa.y * nw1[k] + xa.z * nw1[64 + k] + xa.w * nw1[128 + k]
                      + xb.x * nw1[192 + k] + xb.y * nw1[256 + k];
            HT[k * 68 + lane] = fmaxf(acc, 0.0f);   // conflict-free: banks = 4k+lane
        }
    }
    __syncthreads();

    // ================= P1: GEMMs (waves 0,1) + avec (wave 2) =================
    if (wave < 2) {
        const float* HT = (wave == 0) ? sh_hT1 : sh_hT2;
        float* F = (wave == 0) ? sh_f1 : sh_f2;
        const int rr = lane >> 2, oq = lane & 3;   // rows 4rr..+3; col-quads 4oq, 16+4oq
        float4 accA[4], accB[4];
        #pragma unroll
        for (int m = 0; m < 4; ++m) { accA[m] = make_float4(0,0,0,0); accB[m] = accA[m]; }
        #pragma unroll 4
        for (int k = 0; k < 64; ++k) {
            float4 hq = *(const float4*)(HT + k * 68 + 4 * rr);
            float4 wA = *(const float4*)(sh_w2 + k * 32 + 4 * oq);
            float4 wB = *(const float4*)(sh_w2 + k * 32 + 16 + 4 * oq);
            fma4(accA[0], hq.x, wA); fma4(accB[0], hq.x, wB);
            fma4(accA[1], hq.y, wA); fma4(accB[1], hq.y, wB);
            fma4(accA[2], hq.z, wA); fma4(accB[2], hq.z, wB);
            fma4(accA[3], hq.w, wA); fma4(accB[3], hq.w, wB);
        }
        float4 b2a = *(const float4*)(sh_nb2 + 4 * oq);
        float4 b2b = *(const float4*)(sh_nb2 + 16 + 4 * oq);
        float sq[4];
        #pragma unroll
        for (int m = 0; m < 4; ++m) {
            add4(accA[m], b2a); add4(accB[m], b2b);
            int row = 4 * rr + m;
            *(float4*)(F + row * 36 + 4 * oq)      = accA[m];
            *(float4*)(F + row * 36 + 16 + 4 * oq) = accB[m];
            float q = dot4(accA[m], accA[m]) + dot4(accB[m], accB[m]);
            q += dppf<0xB1>(q); q += dppf<0x4E>(q);    // sum over oq (lane bits 0-1)
            sq[m] = q;
        }
        if (oq == 0) {
            #pragma unroll
            for (int m = 0; m < 4; ++m) {
                int row = 4 * rr + m, p = 4 * (row & 15) + (row >> 4);
                float n = fmaxf(sqrtf(sq[m]), 1e-8f);
                if (wave == 0) { sh_n1[row] = n; sh_n1p[p] = n; }
                else           { sh_n2p[p] = n; }
            }
        }
    } else if (wave == 2 && lane < 16) {   // avec
        int o = lane;
        float ax = 0, av = 0, as_ = 0, aw = 0, au = 0, ae = 0, a1 = 0;
        for (int k = 0; k < 16; ++k) {
            float s0k = sw0[k], c0k = cw0[k], b0k = sb0[k] + cb0[k];
            float s1ko = sw1[k * 16 + o], c1ko = cw1[k * 16 + o];
            ax += s0k * s1ko;  av += c0k * s1ko + s0k * c1ko;  as_ += s1ko;
            aw += c0k * c1ko;  au += c1ko;  ae += b0k * c1ko;  a1 += b0k * s1ko;
        }
        a1 += sb1[o] + cb1[o];
        sh_avec[0*16+o] = ax; sh_avec[1*16+o] = av; sh_avec[2*16+o] = as_;
        sh_avec[3*16+o] = aw; sh_avec[4*16+o] = au; sh_avec[5*16+o] = ae;
        sh_avec[6*16+o] = a1;
    }
    __syncthreads();

    // ================= P2: dots (waves 0-3) + mm/degree consts (all) + coef (wave 4) ==
    if (wave < 4) {
        const int sc = lane & 15, rc = lane >> 4;
        float dt[4][4];
        #pragma unroll
        for (int m = 0; m < 4; ++m)
            #pragma unroll
            for (int k = 0; k < 4; ++k) dt[m][k] = 0.0f;
        for (int kq = 0; kq < 8; ++kq) {
            float4 f2q[4];
            #pragma unroll
            for (int k = 0; k < 4; ++k)
                f2q[k] = *(const float4*)(sh_f2 + (sc + 16 * k) * 36 + 4 * kq);
            #pragma unroll
            for (int m = 0; m < 4; ++m) {
                int rrow = 16 * m + 4 * wave + rc;
                float4 f1q = *(const float4*)(sh_f1 + rrow * 36 + 4 * kq);
                #pragma unroll
                for (int k = 0; k < 4; ++k) dt[m][k] += dot4(f1q, f2q[k]);
            }
        }
        #pragma unroll
        for (int m = 0; m < 4; ++m) {
            int rrow = 16 * m + 4 * wave + rc;
            *(float4*)(sh_dots + rrow * 68 + 4 * sc) =
                make_float4(dt[m][0], dt[m][1], dt[m][2], dt[m][3]);
        }
    } else if (wave == 4 && lane < 18) {   // coef (avec from P1)
        int t = lane; float c = 0.0f;
        if (t == 0)      { for (int k = 0; k < 16; ++k) c += sw0[k] * kw0[k]; }
        else if (t == 1) { for (int k = 0; k < 16; ++k) c += cw0[k] * kw0[k]; }
        else if (t == 2) { for (int k = 0; k < 16; ++k) c += (sb0[k] + cb0[k]) * kw0[k]; c += kb0[0]; }
        else if (t < 10) { int v = t - 3;
            for (int o = 0; o < 16; ++o) c += sh_avec[v * 16 + o] * kw1[o];
            if (v == 6) c += kb1[0];
        } else if (t < 17) { int v = t - 10;
            for (int o = 0; o < 16; ++o) c += sh_avec[v * 16 + o] * fcw[o];
            if (v == 6) c += fcb[0];
        } else { for (int o = 0; o < 16; ++o) c += fcw[o]; }
        sh_coef[t] = c;
    }
    // mm both orientations + degrees via red16 (registers)
    float mmq[4], mmt[4], cfq[4], cft[4];
    float Drr, Dcr;
    {
        const float cls1r = sh_cls1[r], cls2r = sh_cls2p[pr];
        const float cf1r = sh_cf1[r],  cf2r  = sh_cf2p[pr];
        float c2q[4], c1q[4], f2q[4], f1q[4];
        ld4(sh_cls2p + 4*s, c2q); ld4(sh_cls1p + 4*s, c1q);
        ld4(sh_cf2p + 4*s, f2q);  ld4(sh_cf1p + 4*s, f1q);
        float dr = 0, dc = 0;
        #pragma unroll
        for (int k = 0; k < 4; ++k) {
            mmq[k] = (cls1r == c2q[k]) ? 1.0f : 0.0f;
            mmt[k] = (c1q[k] == cls2r) ? 1.0f : 0.0f;
            dr += mmq[k]; dc += mmt[k];
            cfq[k] = sqrtf(cf1r * f2q[k]);
            cft[k] = sqrtf(f1q[k] * cf2r);
        }
        Drr = red16_sum(dr);   // degree of row r
        Dcr = red16_sum(dc);   // degree of col r
        if (s == 0) { sh_Drp[pr] = Drr; sh_Dcp[pr] = Dcr; }
    }
    __syncthreads();

    // ================= P3: dinv + x0, both orientations =================
    float dqv[4], dqt[4], x0[4], x0t[4];
    {
        float dcq[4], drq[4], n2q[4], n1q[4], dotq[4];
        ld4(sh_Dcp + 4*s, dcq); ld4(sh_Drp + 4*s, drq);
        ld4(sh_n2p + 4*s, n2q); ld4(sh_n1p + 4*s, n1q);
        ld4(sh_dots + r * 68 + 4*s, dotq);
        float Tdeg = red16_sum(dcq[0] + dcq[1] + dcq[2] + dcq[3]);
        const float n1r = sh_n1[r], n2r = sh_n2p[pr];
        #pragma unroll
        for (int k = 0; k < 4; ++k) {
            dqv[k] = (mmq[k] != 0.0f) ? (1.0f / sqrtf(Tdeg - Drr - dcq[k] + 3.0f)) : 1.0f;
            dqt[k] = (mmt[k] != 0.0f) ? (1.0f / sqrtf(Tdeg - drq[k] - Dcr + 3.0f)) : 1.0f;
            x0[k] = mmq[k] * cfq[k] * (dotq[k] / (n1r * n2q[k]));
            float dott = sh_dots[(s + 16 * k) * 68 + pr];
            x0t[k] = mmt[k] * cft[k] * (dott / (n1q[k] * n2r));
        }
    }

    // ================= matvec A: v0 = normA x0, oe = normA 1 (both orientations) ======
    float v0[4], v0t[4], oe[4], oet[4];
    {
        float ones[4] = {1.0f, 1.0f, 1.0f, 1.0f};
        matvec_dual(x0, x0t, ones, ones, mmq, dqv, mmt, dqt,
                    v0, v0t, oe, oet, s, pr, sh_WR1p, sh_WC1p, sh_WR2p, sh_WC2p);
    }

    // ================= t0 -> sinkhorn0 -> s0 (both orientations) =================
    float aq[4], att[4], u0, vv0;
    float s0[4], s0t[4];
    {
        float c0 = sh_coef[0], c1 = sh_coef[1], c2 = sh_coef[2];
        float t0q[4], t0t[4];
        #pragma unroll
        for (int k = 0; k < 4; ++k) {
            t0q[k] = (c0 * x0[k]  + c1 * v0[k]  + c2) * SK_SCALE;
            t0t[k] = (c0 * x0t[k] + c1 * v0t[k] + c2) * SK_SCALE;
        }
        sk_mult(t0q, t0t, s, pr, sh_up, sh_vp, sh_rmp, aq, att, &u0, &vv0);
        float vq[4], uq[4];
        ld4(sh_vp + 4*s, vq); ld4(sh_up + 4*s, uq);
        #pragma unroll
        for (int k = 0; k < 4; ++k) {
            s0[k]  = aq[k] * u0 * vq[k];
            s0t[k] = att[k] * uq[k] * vv0;
        }
    }

    // ================= matvec B (v0, s0) + tacc/sacc =================
    float ov[4], ovt[4], os[4], ost[4];
    matvec_dual(v0, v0t, s0, s0t, mmq, dqv, mmt, dqt,
                ov, ovt, os, ost, s, pr, sh_WR1p, sh_WC1p, sh_WR2p, sh_WC2p);
    float t1q[4], t1t[4], sacc[4], sacct[4];
    {
        float ctx = sh_coef[3], ctv = sh_coef[4], cts = sh_coef[5];
        float cw_ = sh_coef[6], cu_ = sh_coef[7], ce_ = sh_coef[8], ct1 = sh_coef[9];
        float csx = sh_coef[10], csv = sh_coef[11], css = sh_coef[12];
        float cw2 = sh_coef[13], cu2 = sh_coef[14], ce2 = sh_coef[15], cs1 = sh_coef[16];
        #pragma unroll
        for (int k = 0; k < 4; ++k) {
            t1q[k] = (ctx * x0[k] + ctv * v0[k] + cts * s0[k] + ct1
                    + cw_ * ov[k] + cu_ * os[k] + ce_ * oe[k]) * SK_SCALE;
            t1t[k] = (ctx * x0t[k] + ctv * v0t[k] + cts * s0t[k] + ct1
                    + cw_ * ovt[k] + cu_ * ost[k] + ce_ * oet[k]) * SK_SCALE;
            sacc[k] = csx * x0[k] + csv * v0[k] + css * s0[k] + cs1
                    + cw2 * ov[k] + cu2 * os[k] + ce2 * oe[k];
            sacct[k] = csx * x0t[k] + csv * v0t[k] + css * s0t[k] + cs1
                    + cw2 * ovt[k] + cu2 * ost[k] + ce2 * oet[k];
        }
    }

    // ================= sinkhorn1 -> sacc += c17*s1 (both orientations) ==============
    {
        float u1, v1;
        sk_mult(t1q, t1t, s, pr, sh_up, sh_vp, sh_rmp, aq, att, &u1, &v1);
        float c17 = sh_coef[17];
        float vq[4], uq[4];
        ld4(sh_vp + 4*s, vq); ld4(sh_up + 4*s, uq);
        #pragma unroll
        for (int k = 0; k < 4; ++k) {
            sacc[k]  += c17 * aq[k] * u1 * vq[k];
            sacct[k] += c17 * att[k] * uq[k] * v1;
        }
    }
    __syncthreads();   // protect up/vp reads before sinkhorn2's pre-barrier writes

    // ================= sinkhorn2 on s = sacc^T -> output =================
    {
        float t2q[4], t2t[4];
        #pragma unroll
        for (int k = 0; k < 4; ++k) {
            t2q[k] = sacct[k] * SK_SCALE;   // s[r][s+16k] = sacc^T
            t2t[k] = sacc[k] * SK_SCALE;
        }
        float u2, v2;
        sk_mult(t2q, t2t, s, pr, sh_up, sh_vp, sh_rmp, aq, att, &u2, &v2);
        float vq[4]; ld4(sh_vp + 4*s, vq);
        #pragma unroll
        for (int k = 0; k < 4; ++k)
            out[(r << 6) + s + (k << 4)] = aq[k] * u2 * vq[k];
    }
}

extern "C" void kernel_launch(void* const* d_in, const int* in_sizes, int n_in,
                              void* d_out, int out_size, void* d_ws, size_t ws_size,
                              hipStream_t stream) {
    const float* ego = (const float*)d_in[0];
    const float* cav = (const float*)d_in[1];
    const float* nw1 = (const float*)d_in[2];
    const float* nb1 = (const float*)d_in[3];
    const float* nw2 = (const float*)d_in[4];
    const float* nb2 = (const float*)d_in[5];
    // d_in[6..9] = edge MLP weights: dead code (edge values only feed the (K!=0) pattern)
    const float* sw0 = (const float*)d_in[10];
    const float* sb0 = (const float*)d_in[11];
    const float* cw0 = (const float*)d_in[12];
    const float* cb0 = (const float*)d_in[13];
    const float* kw0 = (const float*)d_in[14];
    const float* kb0 = (const float*)d_in[15];
    const float* sw1 = (const float*)d_in[16];
    const float* sb1 = (const float*)d_in[17];
    const float* cw1 = (const float*)d_in[18];
    const float* cb1 = (const float*)d_in[19];
    const float* kw1 = (const float*)d_in[20];
    const float* kb1 = (const float*)d_in[21];
    const float* fcw = (const float*)d_in[22];
    const float* fcb = (const float*)d_in[23];

    gcn_match_kernel<<<dim3(1), dim3(1024), 0, stream>>>(
        ego, cav, nw1, nb1, nw2, nb2,
        sw0, sb0, cw0, cb0, kw0, kb0,
        sw1, sb1, cw1, cb1, kw1, kb1,
        fcw, fcb, (float*)d_out);
}

// Round 7
// 123.537 us; speedup vs baseline: 2.2524x; 1.0030x over previous
//
#include <hip/hip_runtime.h>
#include <math.h>

// GCN graph-matching net. Verified reductions (R0-R5, absmax ~0):
//  - K off-diag values only used via (K != 0) -> class-match pattern; edge MLPs dead.
//  - normA @ u collapses to O(N) inclusion-exclusion; x stays rank<=7.
//  - Multiplicative sinkhorn: A = 2^(t - rowmax) once; steps u=1/(Av), v=1/(A^T u).
// R6: 4-WAVE kernel (256 threads). R5 showed the 16-wave version is bound by the ~66
//   workgroup barriers (~850 cyc each: arrival skew + issue), not LDS/VALU throughput.
//   Thread (r=tid>>2, q=tid&3) owns 16 row-elems (row r, cols 16q..16q+15) and 16
//   col-elems (col r, rows 16q..16q+15). Reductions: sum16-in-thread + 2-op quad-DPP.
//   All vectors in natural layout; dots stored natural AND transposed; everything else
//   structurally as R5 (dual-orientation registers, 1-barrier matvecs).

#define SK_SCALE 28.853900817779268f   // (1/TAU = 20) * log2(e)

template<int CTRL>
__device__ __forceinline__ float dppf(float x) {
    int xi = __float_as_int(x);
    int rr = __builtin_amdgcn_update_dpp(xi, xi, CTRL, 0xF, 0xF, false);
    return __int_as_float(rr);
}
__device__ __forceinline__ float quad_sum(float v) {   // sum over lane&3 quad
    v += dppf<0xB1>(v); v += dppf<0x4E>(v); return v;
}
__device__ __forceinline__ float quad_max(float v) {
    v = fmaxf(v, dppf<0xB1>(v)); v = fmaxf(v, dppf<0x4E>(v)); return v;
}
__device__ __forceinline__ float e2f(float x) { return __builtin_amdgcn_exp2f(x); }
__device__ __forceinline__ float rcpf(float x) { return __builtin_amdgcn_rcpf(x); }
__device__ __forceinline__ float dot4(const float4 a, const float4 b) {
    return a.x*b.x + a.y*b.y + a.z*b.z + a.w*b.w;
}
__device__ __forceinline__ void fma4(float4& a, float b, const float4 c) {
    a.x += b*c.x; a.y += b*c.y; a.z += b*c.z; a.w += b*c.w;
}
__device__ __forceinline__ void add4(float4& a, const float4 c) {
    a.x += c.x; a.y += c.y; a.z += c.z; a.w += c.w;
}
__device__ __forceinline__ void ld16(const float* p, float* o) {
    #pragma unroll
    for (int t = 0; t < 4; ++t) {
        float4 v = *(const float4*)(p + 4*t);
        o[4*t+0]=v.x; o[4*t+1]=v.y; o[4*t+2]=v.z; o[4*t+3]=v.w;
    }
}
__device__ __forceinline__ float dotsum16(const float* a, const float* b) {
    float s0=0,s1=0,s2=0,s3=0;
    #pragma unroll
    for (int t = 0; t < 4; ++t) {
        s0 += a[4*t+0]*b[4*t+0]; s1 += a[4*t+1]*b[4*t+1];
        s2 += a[4*t+2]*b[4*t+2]; s3 += a[4*t+3]*b[4*t+3];
    }
    return (s0+s1)+(s2+s3);
}
__device__ __forceinline__ float sum16(const float* a) {
    float s0=0,s1=0,s2=0,s3=0;
    #pragma unroll
    for (int t = 0; t < 4; ++t) {
        s0 += a[4*t+0]; s1 += a[4*t+1]; s2 += a[4*t+2]; s3 += a[4*t+3];
    }
    return (s0+s1)+(s2+s3);
}

// Multiplicative sinkhorn, 20 steps, 20 barriers. tq: row r, cols 16q+m (log2-domain,
// pre-scaled); tt: rows 16q+m, col r. Leaves A in aq/att, final u (it18) / v (it19).
__device__ __forceinline__ void sk_mult(const float* tq, const float* tt, int q, int r,
                                        float* up, float* vp, float* rmp,
                                        float* aq, float* att, float* u_out, float* v_out) {
    float rm = tq[0];
    #pragma unroll
    for (int m = 1; m < 16; ++m) rm = fmaxf(rm, tq[m]);
    rm = quad_max(rm);
    #pragma unroll
    for (int m = 0; m < 16; ++m) aq[m] = e2f(tq[m] - rm);
    float u = rcpf(quad_sum(sum16(aq)));          // it0 (row, v=1)
    if (q == 0) { rmp[r] = rm; up[r] = u; }
    __syncthreads();
    float rmq[16]; ld16(rmp + 16*q, rmq);
    #pragma unroll
    for (int m = 0; m < 16; ++m) att[m] = e2f(tt[m] - rmq[m]);
    float v;
    {   // it1 (col)
        float uq[16]; ld16(up + 16*q, uq);
        v = rcpf(quad_sum(dotsum16(att, uq)));
        if (q == 0) vp[r] = v;
        __syncthreads();
    }
    #pragma unroll 1
    for (int p = 0; p < 9; ++p) {                 // its 2..19
        float vq[16]; ld16(vp + 16*q, vq);
        u = rcpf(quad_sum(dotsum16(aq, vq)));
        if (q == 0) up[r] = u;
        __syncthreads();
        float uq[16]; ld16(up + 16*q, uq);
        v = rcpf(quad_sum(dotsum16(att, uq)));
        if (q == 0) vp[r] = v;
        __syncthreads();
    }
    *u_out = u; *v_out = v;
}

// normA matvec, dual vectors x dual orientations, ONE barrier. u2==nullptr -> ones.
__device__ __forceinline__ void matvec_dual(const float* u1, const float* u1t,
                                            const float* u2, const float* u2t,
                                            const float* mmq, const float* dqv,
                                            const float* mmt, const float* dqt,
                                            float* o1, float* o1t, float* o2, float* o2t,
                                            int q, int r,
                                            float* WR1, float* WC1, float* WR2, float* WC2) {
    float rs1=0, rs2=0, cs1=0, cs2=0;
    #pragma unroll
    for (int m = 0; m < 16; ++m) {
        float md = mmq[m]*dqv[m], mdt = mmt[m]*dqt[m];
        rs1 += md * u1[m];               cs1 += mdt * u1t[m];
        rs2 += md * (u2 ? u2[m] : 1.0f); cs2 += mdt * (u2t ? u2t[m] : 1.0f);
    }
    rs1 = quad_sum(rs1); rs2 = quad_sum(rs2);
    cs1 = quad_sum(cs1); cs2 = quad_sum(cs2);
    if (q == 0) { WR1[r]=rs1; WR2[r]=rs2; WC1[r]=cs1; WC2[r]=cs2; }
    __syncthreads();
    float wr1[16], wc1[16], wr2[16], wc2[16];
    ld16(WR1 + 16*q, wr1); ld16(WC1 + 16*q, wc1);
    ld16(WR2 + 16*q, wr2); ld16(WC2 + 16*q, wc2);
    float W1 = quad_sum(sum16(wc1));
    float W2 = quad_sum(sum16(wc2));
    #pragma unroll
    for (int m = 0; m < 16; ++m) {
        float d = dqv[m], mm = mmq[m];
        float u1m = u1[m], u2m = u2 ? u2[m] : 1.0f;
        float z1 = mm*d*u1m, z2 = mm*d*u2m;
        o1[m] = d*((1.0f+mm)*d*u1m + mm*(W1 - rs1 - wc1[m] + z1));
        o2[m] = d*((1.0f+mm)*d*u2m + mm*(W2 - rs2 - wc2[m] + z2));
        float dt = dqt[m], mt = mmt[m];
        float u1tm = u1t[m], u2tm = u2t ? u2t[m] : 1.0f;
        float z1t = mt*dt*u1tm, z2t = mt*dt*u2tm;
        o1t[m] = dt*((1.0f+mt)*dt*u1tm + mt*(W1 - wr1[m] - cs1 + z1t));
        o2t[m] = dt*((1.0f+mt)*dt*u2tm + mt*(W2 - wr2[m] - cs2 + z2t));
    }
}

extern "C" __global__ __launch_bounds__(256, 1)
void gcn_match_kernel(const float* ego, const float* cav,
                      const float* nw1, const float* nb1, const float* nw2, const float* nb2,
                      const float* sw0, const float* sb0, const float* cw0, const float* cb0,
                      const float* kw0, const float* kb0,
                      const float* sw1, const float* sb1, const float* cw1, const float* cb1,
                      const float* kw1, const float* kb1,
                      const float* fcw, const float* fcb,
                      float* out) {
    __shared__ __align__(16) float sh_hT1[64 * 68];   // ego h^T | later dots (natural)
    __shared__ __align__(16) float sh_hT2[64 * 68];   // cav h^T | later dots^T
    __shared__ __align__(16) float sh_w2[2048];
    __shared__ __align__(16) float sh_f1[64 * 36];
    __shared__ __align__(16) float sh_f2[64 * 36];
    __shared__ __align__(16) float sh_nw1[320];
    __shared__ __align__(16) float sh_nb1[64], sh_nb2[32];
    __shared__ __align__(16) float sh_cls1[64], sh_cf1[64], sh_cls2[64], sh_cf2[64];
    __shared__ __align__(16) float sh_n1[64], sh_n2[64], sh_Dr[64], sh_Dc[64];
    __shared__ __align__(16) float sh_up[64], sh_vp[64], sh_rmp[64];
    __shared__ __align__(16) float sh_WR1[64], sh_WC1[64], sh_WR2[64], sh_WC2[64];
    __shared__ __align__(16) float sh_sw0[16], sh_sb0[16], sh_cw0[16], sh_cb0[16];
    __shared__ __align__(16) float sh_sb1[16], sh_cb1[16];
    __shared__ __align__(16) float sh_sw1[256], sh_cw1[256];
    __shared__ __align__(16) float sh_kw0[16], sh_kw1[16], sh_fcw[16];
    __shared__ float sh_kb[4];        // kb0, kb1, fcb
    __shared__ float sh_avec[7 * 16];
    __shared__ float sh_coef[18];

    const int tid = threadIdx.x;
    const int wv = tid >> 6, lane = tid & 63;
    const int r = tid >> 2, q = tid & 3;

    // ================= P0a: stage everything (one parallel load round) ==========
    ((float4*)sh_w2)[tid]       = ((const float4*)nw2)[tid];
    ((float4*)sh_w2)[tid + 256] = ((const float4*)nw2)[tid + 256];
    if (tid < 80)       ((float4*)sh_nw1)[tid]      = ((const float4*)nw1)[tid];
    else if (tid < 96)  ((float4*)sh_nb1)[tid-80]   = ((const float4*)nb1)[tid-80];
    else if (tid < 104) ((float4*)sh_nb2)[tid-96]   = ((const float4*)nb2)[tid-96];
    else if (tid < 108) ((float4*)sh_sw0)[tid-104]  = ((const float4*)sw0)[tid-104];
    else if (tid < 112) ((float4*)sh_sb0)[tid-108]  = ((const float4*)sb0)[tid-108];
    else if (tid < 116) ((float4*)sh_cw0)[tid-112]  = ((const float4*)cw0)[tid-112];
    else if (tid < 120) ((float4*)sh_cb0)[tid-116]  = ((const float4*)cb0)[tid-116];
    else if (tid < 124) ((float4*)sh_sb1)[tid-120]  = ((const float4*)sb1)[tid-120];
    else if (tid < 128) ((float4*)sh_cb1)[tid-124]  = ((const float4*)cb1)[tid-124];
    else if (tid < 192) ((float4*)sh_sw1)[tid-128]  = ((const float4*)sw1)[tid-128];
    else                ((float4*)sh_cw1)[tid-192]  = ((const float4*)cw1)[tid-192];
    if (tid < 4)        ((float4*)sh_kw0)[tid]      = ((const float4*)kw0)[tid];
    else if (tid < 8)   ((float4*)sh_kw1)[tid-4]    = ((const float4*)kw1)[tid-4];
    else if (tid < 12)  ((float4*)sh_fcw)[tid-8]    = ((const float4*)fcw)[tid-8];
    else if (tid == 12) sh_kb[0] = kb0[0];
    else if (tid == 13) sh_kb[1] = kb1[0];
    else if (tid == 14) sh_kb[2] = fcb[0];
    if (tid < 64) { sh_cls1[tid] = ego[tid*8+6]; sh_cf1[tid] = ego[tid*8+7]; }
    else if (tid < 128) { int j = tid-64; sh_cls2[j] = cav[j*8+6]; sh_cf2[j] = cav[j*8+7]; }
    __syncthreads();

    // ================= P0b: hidden MLP (transposed store), 4 waves ==============
    {
        float4 ea = ((const float4*)ego)[lane*2], eb = ((const float4*)ego)[lane*2+1];
        float4 ca = ((const float4*)cav)[lane*2], cb = ((const float4*)cav)[lane*2+1];
        #pragma unroll
        for (int kk = 0; kk < 16; ++kk) {
            int k = 16*wv + kk;
            float b1 = sh_nb1[k];
            float w0 = sh_nw1[k],       w1 = sh_nw1[64+k],  w2_ = sh_nw1[128+k];
            float w3 = sh_nw1[192+k],   w4 = sh_nw1[256+k];
            sh_hT1[k*68 + lane] = fmaxf(b1 + ea.y*w0 + ea.z*w1 + ea.w*w2_ + eb.x*w3 + eb.y*w4, 0.0f);
            sh_hT2[k*68 + lane] = fmaxf(b1 + ca.y*w0 + ca.z*w1 + ca.w*w2_ + cb.x*w3 + cb.y*w4, 0.0f);
        }
    }
    __syncthreads();

    // ================= P1: GEMMs (waves 0,1) + avec/coef (wave 2) ===============
    if (wv < 2) {
        const float* HT = (wv == 0) ? sh_hT1 : sh_hT2;
        float* F  = (wv == 0) ? sh_f1 : sh_f2;
        float* NN = (wv == 0) ? sh_n1 : sh_n2;
        const int rr = lane >> 2, oq = lane & 3;
        float4 accA[4], accB[4];
        #pragma unroll
        for (int m = 0; m < 4; ++m) { accA[m] = make_float4(0,0,0,0); accB[m] = accA[m]; }
        #pragma unroll 4
        for (int k = 0; k < 64; ++k) {
            float4 hq = *(const float4*)(HT + k*68 + 4*rr);
            float4 wA = *(const float4*)(sh_w2 + k*32 + 4*oq);
            float4 wB = *(const float4*)(sh_w2 + k*32 + 16 + 4*oq);
            fma4(accA[0], hq.x, wA); fma4(accB[0], hq.x, wB);
            fma4(accA[1], hq.y, wA); fma4(accB[1], hq.y, wB);
            fma4(accA[2], hq.z, wA); fma4(accB[2], hq.z, wB);
            fma4(accA[3], hq.w, wA); fma4(accB[3], hq.w, wB);
        }
        float4 b2a = *(const float4*)(sh_nb2 + 4*oq);
        float4 b2b = *(const float4*)(sh_nb2 + 16 + 4*oq);
        float sq[4];
        #pragma unroll
        for (int m = 0; m < 4; ++m) {
            add4(accA[m], b2a); add4(accB[m], b2b);
            int row = 4*rr + m;
            *(float4*)(F + row*36 + 4*oq)      = accA[m];
            *(float4*)(F + row*36 + 16 + 4*oq) = accB[m];
            float q2 = dot4(accA[m], accA[m]) + dot4(accB[m], accB[m]);
            q2 += dppf<0xB1>(q2); q2 += dppf<0x4E>(q2);
            sq[m] = q2;
        }
        if (oq == 0) {
            #pragma unroll
            for (int m = 0; m < 4; ++m)
                NN[4*rr + m] = fmaxf(sqrtf(sq[m]), 1e-8f);
        }
    } else if (wv == 2) {
        if (lane < 16) {   // avec from LDS-staged weights
            int o = lane;
            float ax=0, av=0, as_=0, aw=0, au=0, ae=0, a1=0;
            #pragma unroll
            for (int k = 0; k < 16; ++k) {
                float s0k = sh_sw0[k], c0k = sh_cw0[k], b0k = sh_sb0[k] + sh_cb0[k];
                float s1ko = sh_sw1[k*16+o], c1ko = sh_cw1[k*16+o];
                ax += s0k*s1ko;  av += c0k*s1ko + s0k*c1ko;  as_ += s1ko;
                aw += c0k*c1ko;  au += c1ko;  ae += b0k*c1ko;  a1 += b0k*s1ko;
            }
            a1 += sh_sb1[o] + sh_cb1[o];
            sh_avec[0*16+o]=ax; sh_avec[1*16+o]=av; sh_avec[2*16+o]=as_;
            sh_avec[3*16+o]=aw; sh_avec[4*16+o]=au; sh_avec[5*16+o]=ae;
            sh_avec[6*16+o]=a1;
        }
        if (lane < 18) {   // coef (same wave: avec writes visible via lgkmcnt)
            int t = lane; float c = 0.0f;
            if (t == 0)      { for (int k = 0; k < 16; ++k) c += sh_sw0[k]*sh_kw0[k]; }
            else if (t == 1) { for (int k = 0; k < 16; ++k) c += sh_cw0[k]*sh_kw0[k]; }
            else if (t == 2) { for (int k = 0; k < 16; ++k) c += (sh_sb0[k]+sh_cb0[k])*sh_kw0[k]; c += sh_kb[0]; }
            else if (t < 10) { int v = t-3;
                for (int o = 0; o < 16; ++o) c += sh_avec[v*16+o]*sh_kw1[o];
                if (v == 6) c += sh_kb[1];
            } else if (t < 17) { int v = t-10;
                for (int o = 0; o < 16; ++o) c += sh_avec[v*16+o]*sh_fcw[o];
                if (v == 6) c += sh_kb[2];
            } else { for (int o = 0; o < 16; ++o) c += sh_fcw[o]; }
            sh_coef[t] = c;
        }
    }
    __syncthreads();

    // ================= P2: dots (all 4 waves, natural + transposed) + mm/degrees =
    {
        const int sc = lane & 15, rc = lane >> 4;
        float dt[4][4];
        #pragma unroll
        for (int m = 0; m < 4; ++m)
            #pragma unroll
            for (int k = 0; k < 4; ++k) dt[m][k] = 0.0f;
        for (int kq = 0; kq < 8; ++kq) {
            float4 f2q[4];
            #pragma unroll
            for (int k = 0; k < 4; ++k)
                f2q[k] = *(const float4*)(sh_f2 + (sc + 16*k)*36 + 4*kq);
            #pragma unroll
            for (int m = 0; m < 4; ++m) {
                int rrow = 16*m + 4*wv + rc;
                float4 f1q = *(const float4*)(sh_f1 + rrow*36 + 4*kq);
                #pragma unroll
                for (int k = 0; k < 4; ++k) dt[m][k] += dot4(f1q, f2q[k]);
            }
        }
        #pragma unroll
        for (int m = 0; m < 4; ++m) {
            int rrow = 16*m + 4*wv + rc;
            #pragma unroll
            for (int k = 0; k < 4; ++k) {
                sh_hT1[rrow*68 + sc + 16*k] = dt[m][k];       // dots natural
                sh_hT2[(sc + 16*k)*68 + rrow] = dt[m][k];     // dots transposed
            }
        }
    }
    float mmq[16], mmt[16], cfq[16], cft[16];
    float Drr, Dcr;
    {
        float c2q[16], c1q[16], f2v[16], f1v[16];
        ld16(sh_cls2 + 16*q, c2q); ld16(sh_cls1 + 16*q, c1q);
        ld16(sh_cf2 + 16*q, f2v);  ld16(sh_cf1 + 16*q, f1v);
        const float cls1r = sh_cls1[r], cls2r = sh_cls2[r];
        const float cf1r = sh_cf1[r],  cf2r  = sh_cf2[r];
        float dr = 0, dc = 0;
        #pragma unroll
        for (int m = 0; m < 16; ++m) {
            mmq[m] = (cls1r == c2q[m]) ? 1.0f : 0.0f;
            mmt[m] = (c1q[m] == cls2r) ? 1.0f : 0.0f;
            dr += mmq[m]; dc += mmt[m];
            cfq[m] = sqrtf(cf1r * f2v[m]);
            cft[m] = sqrtf(f1v[m] * cf2r);
        }
        Drr = quad_sum(dr);
        Dcr = quad_sum(dc);
        if (q == 0) { sh_Dr[r] = Drr; sh_Dc[r] = Dcr; }
    }
    __syncthreads();

    // ================= P3: dinv + x0, both orientations ==========================
    float dqv[16], dqt[16], x0[16], x0t[16];
    {
        float dcq[16], drq[16], n2q[16], n1q[16], dotq[16], dotTq[16];
        ld16(sh_Dc + 16*q, dcq); ld16(sh_Dr + 16*q, drq);
        ld16(sh_n2 + 16*q, n2q); ld16(sh_n1 + 16*q, n1q);
        ld16(sh_hT1 + r*68 + 16*q, dotq);
        ld16(sh_hT2 + r*68 + 16*q, dotTq);
        float Tdeg = quad_sum(sum16(dcq));
        const float n1r = sh_n1[r], n2r = sh_n2[r];
        #pragma unroll
        for (int m = 0; m < 16; ++m) {
            dqv[m] = (mmq[m] != 0.0f) ? (1.0f / sqrtf(Tdeg - Drr - dcq[m] + 3.0f)) : 1.0f;
            dqt[m] = (mmt[m] != 0.0f) ? (1.0f / sqrtf(Tdeg - drq[m] - Dcr + 3.0f)) : 1.0f;
            x0[m]  = mmq[m] * cfq[m] * (dotq[m]  / (n1r * n2q[m]));
            x0t[m] = mmt[m] * cft[m] * (dotTq[m] / (n1q[m] * n2r));
        }
    }

    // ================= matvec A: v0 = normA x0, oe = normA 1 =====================
    float v0[16], v0t[16], oe[16], oet[16];
    matvec_dual(x0, x0t, nullptr, nullptr, mmq, dqv, mmt, dqt,
                v0, v0t, oe, oet, q, r, sh_WR1, sh_WC1, sh_WR2, sh_WC2);

    // ================= t0 + fold x0/oe into t1/sacc bases ========================
    float t0q[16], t0t[16], t1b[16], t1bt[16], sbse[16], sbst[16];
    {
        float c0 = sh_coef[0], c1 = sh_coef[1], c2 = sh_coef[2];
        float ctx = sh_coef[3], ctv = sh_coef[4];
        float ce_ = sh_coef[8], ct1 = sh_coef[9];
        float csx = sh_coef[10], csv = sh_coef[11];
        float ce2 = sh_coef[15], cs1 = sh_coef[16];
        #pragma unroll
        for (int m = 0; m < 16; ++m) {
            t0q[m] = (c0*x0[m]  + c1*v0[m]  + c2) * SK_SCALE;
            t0t[m] = (c0*x0t[m] + c1*v0t[m] + c2) * SK_SCALE;
            t1b[m]  = ctx*x0[m]  + ctv*v0[m]  + ct1 + ce_*oe[m];
            t1bt[m] = ctx*x0t[m] + ctv*v0t[m] + ct1 + ce_*oet[m];
            sbse[m] = csx*x0[m]  + csv*v0[m]  + cs1 + ce2*oe[m];
            sbst[m] = csx*x0t[m] + csv*v0t[m] + cs1 + ce2*oet[m];
        }
    }

    // ================= sinkhorn0 -> s0 ===========================================
    float aq[16], att[16], u_, v_;
    sk_mult(t0q, t0t, q, r, sh_up, sh_vp, sh_rmp, aq, att, &u_, &v_);
    float s0v[16], s0t[16];
    {
        float vq[16], uq[16];
        ld16(sh_vp + 16*q, vq); ld16(sh_up + 16*q, uq);
        #pragma unroll
        for (int m = 0; m < 16; ++m) {
            s0v[m] = aq[m] * u_ * vq[m];
            s0t[m] = att[m] * uq[m] * v_;
        }
    }

    // ================= matvec B (v0, s0) -> t1, sacc =============================
    float ov[16], ovt[16], os[16], ost[16];
    matvec_dual(v0, v0t, s0v, s0t, mmq, dqv, mmt, dqt,
                ov, ovt, os, ost, q, r, sh_WR1, sh_WC1, sh_WR2, sh_WC2);
    float t1q[16], t1t[16], sacc[16], sacct[16];
    {
        float cts = sh_coef[5], cw_ = sh_coef[6], cu_ = sh_coef[7];
        float css = sh_coef[12], cw2 = sh_coef[13], cu2 = sh_coef[14];
        #pragma unroll
        for (int m = 0; m < 16; ++m) {
            t1q[m] = (t1b[m]  + cts*s0v[m] + cw_*ov[m]  + cu_*os[m])  * SK_SCALE;
            t1t[m] = (t1bt[m] + cts*s0t[m] + cw_*ovt[m] + cu_*ost[m]) * SK_SCALE;
            sacc[m]  = sbse[m] + css*s0v[m] + cw2*ov[m]  + cu2*os[m];
            sacct[m] = sbst[m] + css*s0t[m] + cw2*ovt[m] + cu2*ost[m];
        }
    }

    // ================= sinkhorn1 -> sacc += c17*s1 ===============================
    sk_mult(t1q, t1t, q, r, sh_up, sh_vp, sh_rmp, aq, att, &u_, &v_);
    {
        float c17 = sh_coef[17];
        float vq[16], uq[16];
        ld16(sh_vp + 16*q, vq); ld16(sh_up + 16*q, uq);
        #pragma unroll
        for (int m = 0; m < 16; ++m) {
            sacc[m]  += c17 * aq[m] * u_ * vq[m];
            sacct[m] += c17 * att[m] * uq[m] * v_;
        }
    }
    __syncthreads();   // protect up/vp reads before sinkhorn2 overwrites

    // ================= sinkhorn2 on s = sacc^T -> output =========================
    {
        float t2q[16], t2t[16];
        #pragma unroll
        for (int m = 0; m < 16; ++m) {
            t2q[m] = sacct[m] * SK_SCALE;   // s[r][16q+m] = Sc(16q+m, r)
            t2t[m] = sacc[m] * SK_SCALE;
        }
        sk_mult(t2q, t2t, q, r, sh_up, sh_vp, sh_rmp, aq, att, &u_, &v_);
        float vq[16]; ld16(sh_vp + 16*q, vq);
        #pragma unroll
        for (int t = 0; t < 4; ++t) {
            float4 o4;
            o4.x = aq[4*t+0] * u_ * vq[4*t+0];
            o4.y = aq[4*t+1] * u_ * vq[4*t+1];
            o4.z = aq[4*t+2] * u_ * vq[4*t+2];
            o4.w = aq[4*t+3] * u_ * vq[4*t+3];
            *(float4*)(out + r*64 + 16*q + 4*t) = o4;
        }
    }
}

extern "C" void kernel_launch(void* const* d_in, const int* in_sizes, int n_in,
                              void* d_out, int out_size, void* d_ws, size_t ws_size,
                              hipStream_t stream) {
    const float* ego = (const float*)d_in[0];
    const float* cav = (const float*)d_in[1];
    const float* nw1 = (const float*)d_in[2];
    const float* nb1 = (const float*)d_in[3];
    const float* nw2 = (const float*)d_in[4];
    const float* nb2 = (const float*)d_in[5];
    // d_in[6..9] = edge MLP weights: dead code (edge values only feed the (K!=0) pattern)
    const float* sw0 = (const float*)d_in[10];
    const float* sb0 = (const float*)d_in[11];
    const float* cw0 = (const float*)d_in[12];
    const float* cb0 = (const float*)d_in[13];
    const float* kw0 = (const float*)d_in[14];
    const float* kb0 = (const float*)d_in[15];
    const float* sw1 = (const float*)d_in[16];
    const float* sb1 = (const float*)d_in[17];
    const float* cw1 = (const float*)d_in[18];
    const float* cb1 = (const float*)d_in[19];
    const float* kw1 = (const float*)d_in[20];
    const float* kb1 = (const float*)d_in[21];
    const float* fcw = (const float*)d_in[22];
    const float* fcb = (const float*)d_in[23];

    gcn_match_kernel<<<dim3(1), dim3(256), 0, stream>>>(
        ego, cav, nw1, nb1, nw2, nb2,
        sw0, sb0, cw0, cb0, kw0, kb0,
        sw1, sb1, cw1, cb1, kw1, kb1,
        fcw, fcb, (float*)d_out);
}